// Round 1
// baseline (601.784 us; speedup 1.0000x reference)
//
#include <hip/hip_runtime.h>

#define N_NODES 20000
#define N_EDGES 320000
#define NBATCH  128

// ---------------------------------------------------------------- h0 = relu(x@W0+b0)
__global__ void k_h0(const float* __restrict__ x, const float* __restrict__ W0,
                     const float* __restrict__ b0, float* __restrict__ h0, int n) {
    __shared__ float ws[25 * 64];
    __shared__ float bs[64];
    int t = threadIdx.x;
    for (int i = t; i < 25 * 64; i += 256) ws[i] = W0[i];
    if (t < 64) bs[t] = b0[t];
    __syncthreads();
    int node = blockIdx.x * 4 + (t >> 6);
    int c = t & 63;
    if (node >= n) return;
    float s = bs[c];
    const float* xr = x + (size_t)node * 25;
    #pragma unroll
    for (int k = 0; k < 25; k++) s += xr[k] * ws[k * 64 + c];
    h0[(size_t)node * 64 + c] = fmaxf(s, 0.f);
}

// ---------------------------------------------------------------- C = act(A[n,K] @ W[K,F] (+bias))
template <int K, int F, int TR, bool RELU>
__global__ void k_linear(const float* __restrict__ A, const float* __restrict__ W,
                         const float* __restrict__ bias, float* __restrict__ C, int nrows) {
    constexpr int CG = F / 4;       // col groups of 4
    constexpr int RS = 256 / CG;    // row slots
    int t = threadIdx.x;
    int cg = t % CG, rs = t / CG;
    int c0 = cg * 4;
    int r0 = blockIdx.x * (RS * TR) + rs * TR;
    float acc[TR][4];
    #pragma unroll
    for (int i = 0; i < TR; i++)
        #pragma unroll
        for (int j = 0; j < 4; j++) acc[i][j] = 0.f;

    for (int k = 0; k < K; k += 4) {
        float4 w[4];
        #pragma unroll
        for (int j = 0; j < 4; j++) w[j] = *(const float4*)(W + (size_t)(k + j) * F + c0);
        #pragma unroll
        for (int i = 0; i < TR; i++) {
            int r = r0 + i;
            if (r < nrows) {
                float4 a = *(const float4*)(A + (size_t)r * K + k);
                acc[i][0] += a.x * w[0].x + a.y * w[1].x + a.z * w[2].x + a.w * w[3].x;
                acc[i][1] += a.x * w[0].y + a.y * w[1].y + a.z * w[2].y + a.w * w[3].y;
                acc[i][2] += a.x * w[0].z + a.y * w[1].z + a.z * w[2].z + a.w * w[3].z;
                acc[i][3] += a.x * w[0].w + a.y * w[1].w + a.z * w[2].w + a.w * w[3].w;
            }
        }
    }
    #pragma unroll
    for (int i = 0; i < TR; i++) {
        int r = r0 + i;
        if (r >= nrows) continue;
        float4 o;
        o.x = acc[i][0]; o.y = acc[i][1]; o.z = acc[i][2]; o.w = acc[i][3];
        if (bias) { o.x += bias[c0]; o.y += bias[c0 + 1]; o.z += bias[c0 + 2]; o.w += bias[c0 + 3]; }
        if (RELU) { o.x = fmaxf(o.x, 0.f); o.y = fmaxf(o.y, 0.f); o.z = fmaxf(o.z, 0.f); o.w = fmaxf(o.w, 0.f); }
        *(float4*)(C + (size_t)r * F + c0) = o;
    }
}

// ---------------------------------------------------------------- per-(node,head) attention dots
__global__ void k_att(const float* __restrict__ xh, const float* __restrict__ att_s,
                      const float* __restrict__ att_d, float* __restrict__ a_s,
                      float* __restrict__ a_d, int n) {
    int i = blockIdx.x * 256 + threadIdx.x;   // i = node*8 + h
    if (i >= n * 8) return;
    int node = i >> 3, h = i & 7;
    const float4* xp = (const float4*)(xh + (size_t)node * 512 + h * 64);
    const float4* sp = (const float4*)(att_s + h * 64);
    const float4* dp = (const float4*)(att_d + h * 64);
    float as = 0.f, ad = 0.f;
    #pragma unroll
    for (int j = 0; j < 16; j++) {
        float4 xv = xp[j], sv = sp[j], dv = dp[j];
        as += xv.x * sv.x + xv.y * sv.y + xv.z * sv.z + xv.w * sv.w;
        ad += xv.x * dv.x + xv.y * dv.y + xv.z * dv.z + xv.w * dv.w;
    }
    a_s[i] = as; a_d[i] = ad;
}

// ---------------------------------------------------------------- CSR build
__global__ void k_count(const int* __restrict__ dst, int* __restrict__ deg, int e) {
    int i = blockIdx.x * 256 + threadIdx.x;
    if (i < e) atomicAdd(&deg[dst[i]], 1);
}

__global__ void k_scan(const int* __restrict__ deg, int* __restrict__ offs, int n) {
    __shared__ int buf[1024];
    __shared__ int carry_s;
    int tid = threadIdx.x;
    if (tid == 0) carry_s = 0;
    __syncthreads();
    for (int base = 0; base < n; base += 1024) {
        int i = base + tid;
        int v = (i < n) ? (deg[i] + 1) : 0;   // +1: self loop
        buf[tid] = v;
        __syncthreads();
        #pragma unroll
        for (int off = 1; off < 1024; off <<= 1) {
            int tv = (tid >= off) ? buf[tid - off] : 0;
            __syncthreads();
            buf[tid] += tv;
            __syncthreads();
        }
        int incl = buf[tid];
        int total = buf[1023];
        int c = carry_s;
        __syncthreads();
        if (i < n) offs[i] = c + incl - v;
        if (tid == 0) carry_s = c + total;
        __syncthreads();
    }
    if (tid == 0) offs[n] = carry_s;
}

__global__ void k_fill_self(const int* __restrict__ offs, int* __restrict__ adj,
                            int* __restrict__ cursor, int n) {
    int i = blockIdx.x * 256 + threadIdx.x;
    if (i >= n) return;
    int o = offs[i];
    adj[o] = i;
    cursor[i] = o + 1;
}

__global__ void k_fill_edge(const int* __restrict__ src, const int* __restrict__ dst,
                            int* __restrict__ cursor, int* __restrict__ adj, int e) {
    int i = blockIdx.x * 256 + threadIdx.x;
    if (i >= e) return;
    int p = atomicAdd(&cursor[dst[i]], 1);
    adj[p] = src[i];
}

// ---------------------------------------------------------------- GAT softmax + aggregate (1 wave / node)
__global__ void k_gat(const int* __restrict__ offs, const int* __restrict__ adj,
                      const float* __restrict__ a_s, const float* __restrict__ a_d,
                      const float* __restrict__ xh, const float* __restrict__ bg,
                      float* __restrict__ agg, int n) {
    int lane = threadIdx.x & 63;
    int node = blockIdx.x * 4 + (threadIdx.x >> 6);
    if (node >= n) return;
    int beg = offs[node], end = offs[node + 1];

    // pass 1: online (max,sum) per head; lane = g*8 + h
    int h = lane & 7, g = lane >> 3;
    float ad = a_d[(size_t)node * 8 + h];
    float m = -1e30f, s = 0.f;
    for (int i = beg + g; i < end; i += 8) {
        int src = adj[i];
        float e = a_s[(size_t)src * 8 + h] + ad;
        e = e > 0.f ? e : 0.2f * e;
        if (e > m) { s = s * __expf(m - e) + 1.f; m = e; }
        else       { s += __expf(e - m); }
    }
    #pragma unroll
    for (int off = 8; off < 64; off <<= 1) {
        float mo = __shfl_xor(m, off);
        float so = __shfl_xor(s, off);
        float mn = fmaxf(m, mo);
        s = s * __expf(m - mn) + so * __expf(mo - mn);
        m = mn;
    }
    // redistribute: lane owns head hl = lane>>3, channels lane*8..lane*8+7
    int hl = lane >> 3;
    float mh = __shfl(m, hl);
    float sh = __shfl(s, hl);
    float rcp = 1.f / sh;
    float adh = a_d[(size_t)node * 8 + hl];

    float acc[8] = {0.f, 0.f, 0.f, 0.f, 0.f, 0.f, 0.f, 0.f};
    for (int i = beg; i < end; ++i) {
        int src = adj[i];
        float e = a_s[(size_t)src * 8 + hl] + adh;
        e = e > 0.f ? e : 0.2f * e;
        float alpha = __expf(e - mh) * rcp;
        const float4* xp = (const float4*)(xh + (size_t)src * 512) + lane * 2;
        float4 x0 = xp[0], x1 = xp[1];
        acc[0] += alpha * x0.x; acc[1] += alpha * x0.y; acc[2] += alpha * x0.z; acc[3] += alpha * x0.w;
        acc[4] += alpha * x1.x; acc[5] += alpha * x1.y; acc[6] += alpha * x1.z; acc[7] += alpha * x1.w;
    }
    float4 bg0 = ((const float4*)bg)[lane * 2], bg1 = ((const float4*)bg)[lane * 2 + 1];
    float4 o0, o1;
    o0.x = fmaxf(acc[0] + bg0.x, 0.f); o0.y = fmaxf(acc[1] + bg0.y, 0.f);
    o0.z = fmaxf(acc[2] + bg0.z, 0.f); o0.w = fmaxf(acc[3] + bg0.w, 0.f);
    o1.x = fmaxf(acc[4] + bg1.x, 0.f); o1.y = fmaxf(acc[5] + bg1.y, 0.f);
    o1.z = fmaxf(acc[6] + bg1.z, 0.f); o1.w = fmaxf(acc[7] + bg1.w, 0.f);
    float4* op = (float4*)(agg + (size_t)node * 512) + lane * 2;
    op[0] = o0; op[1] = o1;
}

// ---------------------------------------------------------------- batch segment bounds (batch sorted)
__global__ void k_bounds(const int* __restrict__ batch, int* __restrict__ segstart, int n, int b) {
    int i = blockIdx.x * 256 + threadIdx.x;
    if (i > b) return;
    int lo = 0, hi = n;
    while (lo < hi) { int mid = (lo + hi) >> 1; if (batch[mid] < i) lo = mid + 1; else hi = mid; }
    segstart[i] = lo;
}

// ---------------------------------------------------------------- Set2Set LSTM step (block per batch row)
__global__ void k_lstm(const float* __restrict__ W_ih, const float* __restrict__ W_hh,
                       const float* __restrict__ b_ih, const float* __restrict__ b_hh,
                       const float* __restrict__ r_in, float* __restrict__ h, float* __restrict__ c) {
    int b = blockIdx.x;
    int g = threadIdx.x;   // 0..255 (gate index)
    __shared__ float gs[256];
    __shared__ float hs[64], rs_[64];
    if (g < 64) hs[g] = h[(size_t)b * 64 + g];
    else if (g < 128) rs_[g - 64] = r_in[(size_t)b * 64 + (g - 64)];
    __syncthreads();
    float acc = b_ih[g] + b_hh[g];
    const float* wi = W_ih + (size_t)g * 128;
    const float* wh = W_hh + (size_t)g * 64;
    #pragma unroll 8
    for (int k = 0; k < 64; k++) acc += hs[k] * (wi[k] + wh[k]) + rs_[k] * wi[64 + k];
    gs[g] = acc;
    __syncthreads();
    if (g < 64) {
        float ig = gs[g], fg = gs[64 + g], gg = gs[128 + g], og = gs[192 + g];
        float cc = c[(size_t)b * 64 + g];
        float si = 1.f / (1.f + __expf(-ig));
        float sf = 1.f / (1.f + __expf(-fg));
        float so = 1.f / (1.f + __expf(-og));
        float cn = sf * cc + si * tanhf(gg);
        c[(size_t)b * 64 + g] = cn;
        h[(size_t)b * 64 + g] = so * tanhf(cn);
    }
}

__global__ void k_e2(const float* __restrict__ out2, const float* __restrict__ h,
                     const int* __restrict__ batch, float* __restrict__ e2, int n) {
    int i = blockIdx.x * 256 + threadIdx.x;
    if (i >= n) return;
    int b = batch[i];
    const float4* op = (const float4*)(out2 + (size_t)i * 64);
    const float4* hp = (const float4*)(h + (size_t)b * 64);
    float s = 0.f;
    #pragma unroll
    for (int j = 0; j < 16; j++) {
        float4 o = op[j], hv = hp[j];
        s += o.x * hv.x + o.y * hv.y + o.z * hv.z + o.w * hv.w;
    }
    e2[i] = s;
}

__global__ void k_seg(const float* __restrict__ e2, const int* __restrict__ segstart,
                      float* __restrict__ m2, float* __restrict__ s2) {
    int b = blockIdx.x, t = threadIdx.x;   // 64 threads
    int beg = segstart[b], end = segstart[b + 1];
    float m = -1e30f;
    for (int i = beg + t; i < end; i += 64) m = fmaxf(m, e2[i]);
    #pragma unroll
    for (int off = 32; off > 0; off >>= 1) m = fmaxf(m, __shfl_xor(m, off));
    float s = 0.f;
    for (int i = beg + t; i < end; i += 64) s += __expf(e2[i] - m);
    #pragma unroll
    for (int off = 32; off > 0; off >>= 1) s += __shfl_xor(s, off);
    if (t == 0) { m2[b] = m; s2[b] = s; }
}

__global__ void k_r(const float* __restrict__ e2, const float* __restrict__ out2,
                    const int* __restrict__ segstart, const float* __restrict__ m2,
                    const float* __restrict__ s2, float* __restrict__ r_out) {
    int b = blockIdx.x, d = threadIdx.x;   // 64 threads
    int beg = segstart[b], end = segstart[b + 1];
    float m = m2[b], sv = s2[b];
    float inv = sv > 0.f ? 1.f / sv : 0.f;
    float acc = 0.f;
    for (int i = beg; i < end; ++i)
        acc += __expf(e2[i] - m) * out2[(size_t)i * 64 + d];
    r_out[(size_t)b * 64 + d] = acc * inv;
}

__global__ void k_final(const float* __restrict__ h, const float* __restrict__ r,
                        const float* __restrict__ W1, const float* __restrict__ b1,
                        const float* __restrict__ W2, const float* __restrict__ b2,
                        float* __restrict__ out) {
    int b = blockIdx.x, j = threadIdx.x;  // 64 threads
    float t = b1[j];
    const float* hb = h + (size_t)b * 64;
    const float* rb = r + (size_t)b * 64;
    #pragma unroll 8
    for (int k = 0; k < 64; k++)
        t += hb[k] * W1[(size_t)k * 64 + j] + rb[k] * W1[(size_t)(64 + k) * 64 + j];
    t = fmaxf(t, 0.f) * W2[j];
    #pragma unroll
    for (int off = 32; off > 0; off >>= 1) t += __shfl_xor(t, off);
    if (j == 0) out[b] = t + b2[0];
}

// ----------------------------------------------------------------
extern "C" void kernel_launch(void* const* d_in, const int* in_sizes, int n_in,
                              void* d_out, int out_size, void* d_ws, size_t ws_size,
                              hipStream_t stream) {
    const float* x     = (const float*)d_in[0];
    const int*   ei    = (const int*)d_in[1];
    const int*   batch = (const int*)d_in[2];
    const float* W0    = (const float*)d_in[3];
    const float* b0    = (const float*)d_in[4];
    const float* Wg    = (const float*)d_in[5];
    const float* att_s = (const float*)d_in[6];
    const float* att_d = (const float*)d_in[7];
    const float* bg    = (const float*)d_in[8];
    const float* Wh    = (const float*)d_in[9];
    const float* bh    = (const float*)d_in[10];
    const float* W_ih  = (const float*)d_in[11];
    const float* W_hh  = (const float*)d_in[12];
    const float* b_ih  = (const float*)d_in[13];
    const float* b_hh  = (const float*)d_in[14];
    const float* W1    = (const float*)d_in[15];
    const float* b1    = (const float*)d_in[16];
    const float* W2    = (const float*)d_in[17];
    const float* b2    = (const float*)d_in[18];
    float* out = (float*)d_out;

    const int* esrc = ei;
    const int* edst = ei + N_EDGES;

    char* wsb = (char*)d_ws;
    size_t off = 0;
    auto alloc = [&](size_t bytes) {
        void* p = wsb + off;
        off = (off + bytes + 255) & ~(size_t)255;
        return p;
    };
    float* h0     = (float*)alloc((size_t)N_NODES * 64 * 4);
    float* xh     = (float*)alloc((size_t)N_NODES * 512 * 4);
    float* a_s    = (float*)alloc((size_t)N_NODES * 8 * 4);
    float* a_d    = (float*)alloc((size_t)N_NODES * 8 * 4);
    float* agg    = (float*)alloc((size_t)N_NODES * 512 * 4);
    float* out2   = (float*)alloc((size_t)N_NODES * 64 * 4);
    float* e2     = (float*)alloc((size_t)N_NODES * 4);
    int*   deg    = (int*)alloc((size_t)N_NODES * 4);
    int*   offs   = (int*)alloc((size_t)(N_NODES + 1) * 4);
    int*   cursor = (int*)alloc((size_t)N_NODES * 4);
    int*   adj    = (int*)alloc((size_t)(N_EDGES + N_NODES) * 4);
    int*   segst  = (int*)alloc((size_t)(NBATCH + 1) * 4);
    float* m2     = (float*)alloc((size_t)NBATCH * 4);
    float* s2     = (float*)alloc((size_t)NBATCH * 4);
    float* hstate = (float*)alloc((size_t)NBATCH * 64 * 4);
    float* cstate = (float*)alloc((size_t)NBATCH * 64 * 4);
    float* r0     = (float*)alloc((size_t)NBATCH * 64 * 4);
    float* r1     = (float*)alloc((size_t)NBATCH * 64 * 4);

    // init
    hipMemsetAsync(deg, 0, (size_t)N_NODES * 4, stream);
    hipMemsetAsync(hstate, 0, (size_t)NBATCH * 64 * 4, stream);
    hipMemsetAsync(cstate, 0, (size_t)NBATCH * 64 * 4, stream);
    hipMemsetAsync(r0, 0, (size_t)NBATCH * 64 * 4, stream);

    // node MLP + GAT projection
    k_h0<<<(N_NODES + 3) / 4, 256, 0, stream>>>(x, W0, b0, h0, N_NODES);
    k_linear<64, 512, 8, false><<<(N_NODES + 15) / 16, 256, 0, stream>>>(h0, Wg, nullptr, xh, N_NODES);
    k_att<<<(N_NODES * 8 + 255) / 256, 256, 0, stream>>>(xh, att_s, att_d, a_s, a_d, N_NODES);

    // CSR by dst (with self loops)
    k_count<<<(N_EDGES + 255) / 256, 256, 0, stream>>>(edst, deg, N_EDGES);
    k_scan<<<1, 1024, 0, stream>>>(deg, offs, N_NODES);
    k_fill_self<<<(N_NODES + 255) / 256, 256, 0, stream>>>(offs, adj, cursor, N_NODES);
    k_fill_edge<<<(N_EDGES + 255) / 256, 256, 0, stream>>>(esrc, edst, cursor, adj, N_EDGES);

    // GAT aggregate + head_nn
    k_gat<<<(N_NODES + 3) / 4, 256, 0, stream>>>(offs, adj, a_s, a_d, xh, bg, agg, N_NODES);
    k_linear<512, 64, 4, true><<<(N_NODES + 63) / 64, 256, 0, stream>>>(agg, Wh, bh, out2, N_NODES);

    // Set2Set
    k_bounds<<<1, 256, 0, stream>>>(batch, segst, N_NODES, NBATCH);
    float* rin = r0;
    float* rout = r1;
    for (int it = 0; it < 3; it++) {
        k_lstm<<<NBATCH, 256, 0, stream>>>(W_ih, W_hh, b_ih, b_hh, rin, hstate, cstate);
        k_e2<<<(N_NODES + 255) / 256, 256, 0, stream>>>(out2, hstate, batch, e2, N_NODES);
        k_seg<<<NBATCH, 64, 0, stream>>>(e2, segst, m2, s2);
        k_r<<<NBATCH, 64, 0, stream>>>(e2, out2, segst, m2, s2, rout);
        float* tmp = rin; rin = rout; rout = tmp;
    }
    // after 3 iters: final r is in `rin` (last written)
    k_final<<<NBATCH, 64, 0, stream>>>(hstate, rin, W1, b1, W2, b2, out);
}

// Round 2
// 418.584 us; speedup vs baseline: 1.4377x; 1.4377x over previous
//
#include <hip/hip_runtime.h>

#define N_NODES 20000
#define N_EDGES 320000
#define NBATCH  128

// ---------------------------------------------------------------- h0 = relu(x@W0+b0)
__global__ void k_h0(const float* __restrict__ x, const float* __restrict__ W0,
                     const float* __restrict__ b0, float* __restrict__ h0, int n) {
    __shared__ float ws[25 * 64];
    __shared__ float bs[64];
    int t = threadIdx.x;
    for (int i = t; i < 25 * 64; i += 256) ws[i] = W0[i];
    if (t < 64) bs[t] = b0[t];
    __syncthreads();
    int node = blockIdx.x * 4 + (t >> 6);
    int c = t & 63;
    if (node >= n) return;
    float s = bs[c];
    const float* xr = x + (size_t)node * 25;
    #pragma unroll
    for (int k = 0; k < 25; k++) s += xr[k] * ws[k * 64 + c];
    h0[(size_t)node * 64 + c] = fmaxf(s, 0.f);
}

// ---------------------------------------------------------------- tiled GEMM C = A[M,K] @ W[K,N]
// 64x64 tile, BK=32, 256 threads, 4x4 micro-tile. Optional split-K partials.
template <int K, int N, int KSPLIT, bool PARTIAL>
__global__ __launch_bounds__(256) void k_gemm(const float* __restrict__ A,
                                              const float* __restrict__ W,
                                              float* __restrict__ C, int M) {
    constexpr int KS = K / KSPLIT;
    __shared__ float As[32 * 65];   // k-major, padded: As[k*65 + m]
    __shared__ float Bs[32 * 64];   // k-major: Bs[k*64 + n]
    int tid = threadIdx.x;
    constexpr int nTilesN = N / 64;
    int bm = blockIdx.x / nTilesN;
    int bn = blockIdx.x % nTilesN;
    int rbase = bm * 64;
    int cbase = bn * 64;
    int kbase0 = blockIdx.y * KS;

    int tx = tid % 16, ty = tid / 16;
    int la_r = tid / 8;          // 0..31
    int la_k = (tid % 8) * 4;    // 0,4,..28
    int lb_k = tid / 16;         // 0..15
    int lb_c = (tid % 16) * 4;

    float acc[4][4] = {};

    for (int kc = 0; kc < KS; kc += 32) {
        int kg = kbase0 + kc;
        #pragma unroll
        for (int rr = 0; rr < 2; rr++) {
            int r = rbase + la_r + rr * 32;
            float4 av = make_float4(0.f, 0.f, 0.f, 0.f);
            if (r < M) av = *(const float4*)(A + (size_t)r * K + kg + la_k);
            int m = la_r + rr * 32;
            As[(la_k + 0) * 65 + m] = av.x;
            As[(la_k + 1) * 65 + m] = av.y;
            As[(la_k + 2) * 65 + m] = av.z;
            As[(la_k + 3) * 65 + m] = av.w;
        }
        #pragma unroll
        for (int kk = 0; kk < 2; kk++) {
            int krow = lb_k + kk * 16;
            *(float4*)&Bs[krow * 64 + lb_c] =
                *(const float4*)(W + (size_t)(kg + krow) * N + cbase + lb_c);
        }
        __syncthreads();
        #pragma unroll
        for (int k = 0; k < 32; k++) {
            float a0 = As[k * 65 + ty * 4 + 0];
            float a1 = As[k * 65 + ty * 4 + 1];
            float a2 = As[k * 65 + ty * 4 + 2];
            float a3 = As[k * 65 + ty * 4 + 3];
            float4 b = *(const float4*)&Bs[k * 64 + tx * 4];
            acc[0][0] += a0 * b.x; acc[0][1] += a0 * b.y; acc[0][2] += a0 * b.z; acc[0][3] += a0 * b.w;
            acc[1][0] += a1 * b.x; acc[1][1] += a1 * b.y; acc[1][2] += a1 * b.z; acc[1][3] += a1 * b.w;
            acc[2][0] += a2 * b.x; acc[2][1] += a2 * b.y; acc[2][2] += a2 * b.z; acc[2][3] += a2 * b.w;
            acc[3][0] += a3 * b.x; acc[3][1] += a3 * b.y; acc[3][2] += a3 * b.z; acc[3][3] += a3 * b.w;
        }
        __syncthreads();
    }

    float* Cb = PARTIAL ? (C + (size_t)blockIdx.y * M * 64) : C;
    #pragma unroll
    for (int i = 0; i < 4; i++) {
        int r = rbase + ty * 4 + i;
        if (r >= M) continue;
        float4 o;
        o.x = acc[i][0]; o.y = acc[i][1]; o.z = acc[i][2]; o.w = acc[i][3];
        *(float4*)(Cb + (size_t)r * N + cbase + tx * 4) = o;
    }
}

// reduce split-K partials + bias + relu
__global__ void k_reduce4(const float* __restrict__ part, const float* __restrict__ bias,
                          float* __restrict__ out, int M) {
    int idx = blockIdx.x * 256 + threadIdx.x;   // one float4 per thread
    if (idx >= M * 16) return;
    int r = idx / 16, cq = idx % 16;
    float4 s = make_float4(0.f, 0.f, 0.f, 0.f);
    #pragma unroll
    for (int y = 0; y < 4; y++) {
        float4 p = *(const float4*)(part + ((size_t)y * M + r) * 64 + cq * 4);
        s.x += p.x; s.y += p.y; s.z += p.z; s.w += p.w;
    }
    float4 b = *(const float4*)(bias + cq * 4);
    s.x = fmaxf(s.x + b.x, 0.f); s.y = fmaxf(s.y + b.y, 0.f);
    s.z = fmaxf(s.z + b.z, 0.f); s.w = fmaxf(s.w + b.w, 0.f);
    *(float4*)(out + (size_t)r * 64 + cq * 4) = s;
}

// ---------------------------------------------------------------- per-(node,head) attention dots
__global__ void k_att(const float* __restrict__ xh, const float* __restrict__ att_s,
                      const float* __restrict__ att_d, float* __restrict__ a_s,
                      float* __restrict__ a_d, int n) {
    int i = blockIdx.x * 256 + threadIdx.x;   // i = node*8 + h
    if (i >= n * 8) return;
    int node = i >> 3, h = i & 7;
    const float4* xp = (const float4*)(xh + (size_t)node * 512 + h * 64);
    const float4* sp = (const float4*)(att_s + h * 64);
    const float4* dp = (const float4*)(att_d + h * 64);
    float as = 0.f, ad = 0.f;
    #pragma unroll
    for (int j = 0; j < 16; j++) {
        float4 xv = xp[j], sv = sp[j], dv = dp[j];
        as += xv.x * sv.x + xv.y * sv.y + xv.z * sv.z + xv.w * sv.w;
        ad += xv.x * dv.x + xv.y * dv.y + xv.z * dv.z + xv.w * dv.w;
    }
    a_s[i] = as; a_d[i] = ad;
}

// ---------------------------------------------------------------- CSR build
__global__ void k_count(const int* __restrict__ dst, int* __restrict__ deg, int e) {
    int i = blockIdx.x * 256 + threadIdx.x;
    if (i < e) atomicAdd(&deg[dst[i]], 1);
}

__global__ void k_scan(const int* __restrict__ deg, int* __restrict__ offs, int n) {
    __shared__ int wsum[16];
    __shared__ int carry_s;
    int tid = threadIdx.x, lane = tid & 63, w = tid >> 6;
    if (tid == 0) carry_s = 0;
    __syncthreads();
    for (int base = 0; base < 20480; base += 1024) {
        int i = base + tid;
        int v = (i < n) ? deg[i] + 1 : 0;   // +1: self loop
        int x = v;
        #pragma unroll
        for (int off = 1; off < 64; off <<= 1) {
            int t = __shfl_up(x, off);
            if (lane >= off) x += t;
        }
        if (lane == 63) wsum[w] = x;
        __syncthreads();
        int wpre = 0, total = 0;
        #pragma unroll
        for (int j = 0; j < 16; j++) { int sv = wsum[j]; total += sv; if (j < w) wpre += sv; }
        int c = carry_s;
        if (i < n) offs[i] = c + wpre + x - v;   // exclusive
        __syncthreads();
        if (tid == 0) carry_s = c + total;
    }
    if (tid == 0) offs[n] = carry_s;
}

__global__ void k_fill_self(const int* __restrict__ offs, int* __restrict__ adj,
                            int* __restrict__ cursor, int n) {
    int i = blockIdx.x * 256 + threadIdx.x;
    if (i >= n) return;
    int o = offs[i];
    adj[o] = i;
    cursor[i] = o + 1;
}

__global__ void k_fill_edge(const int* __restrict__ src, const int* __restrict__ dst,
                            int* __restrict__ cursor, int* __restrict__ adj, int e) {
    int i = blockIdx.x * 256 + threadIdx.x;
    if (i >= e) return;
    int p = atomicAdd(&cursor[dst[i]], 1);
    adj[p] = src[i];
}

// ---------------------------------------------------------------- GAT softmax + aggregate (1 wave / node)
__global__ void k_gat(const int* __restrict__ offs, const int* __restrict__ adj,
                      const float* __restrict__ a_s, const float* __restrict__ a_d,
                      const float* __restrict__ xh, const float* __restrict__ bg,
                      float* __restrict__ agg, int n) {
    int lane = threadIdx.x & 63;
    int node = blockIdx.x * 4 + (threadIdx.x >> 6);
    if (node >= n) return;
    int beg = offs[node], end = offs[node + 1];

    int h = lane & 7, g = lane >> 3;
    float ad = a_d[(size_t)node * 8 + h];
    float m = -1e30f, s = 0.f;
    for (int i = beg + g; i < end; i += 8) {
        int src = adj[i];
        float e = a_s[(size_t)src * 8 + h] + ad;
        e = e > 0.f ? e : 0.2f * e;
        if (e > m) { s = s * __expf(m - e) + 1.f; m = e; }
        else       { s += __expf(e - m); }
    }
    #pragma unroll
    for (int off = 8; off < 64; off <<= 1) {
        float mo = __shfl_xor(m, off);
        float so = __shfl_xor(s, off);
        float mn = fmaxf(m, mo);
        s = s * __expf(m - mn) + so * __expf(mo - mn);
        m = mn;
    }
    int hl = lane >> 3;
    float mh = __shfl(m, hl);
    float sh = __shfl(s, hl);
    float rcp = 1.f / sh;
    float adh = a_d[(size_t)node * 8 + hl];

    float acc[8] = {0.f, 0.f, 0.f, 0.f, 0.f, 0.f, 0.f, 0.f};
    for (int i = beg; i < end; ++i) {
        int src = adj[i];
        float e = a_s[(size_t)src * 8 + hl] + adh;
        e = e > 0.f ? e : 0.2f * e;
        float alpha = __expf(e - mh) * rcp;
        const float4* xp = (const float4*)(xh + (size_t)src * 512) + lane * 2;
        float4 x0 = xp[0], x1 = xp[1];
        acc[0] += alpha * x0.x; acc[1] += alpha * x0.y; acc[2] += alpha * x0.z; acc[3] += alpha * x0.w;
        acc[4] += alpha * x1.x; acc[5] += alpha * x1.y; acc[6] += alpha * x1.z; acc[7] += alpha * x1.w;
    }
    float4 bg0 = ((const float4*)bg)[lane * 2], bg1 = ((const float4*)bg)[lane * 2 + 1];
    float4 o0, o1;
    o0.x = fmaxf(acc[0] + bg0.x, 0.f); o0.y = fmaxf(acc[1] + bg0.y, 0.f);
    o0.z = fmaxf(acc[2] + bg0.z, 0.f); o0.w = fmaxf(acc[3] + bg0.w, 0.f);
    o1.x = fmaxf(acc[4] + bg1.x, 0.f); o1.y = fmaxf(acc[5] + bg1.y, 0.f);
    o1.z = fmaxf(acc[6] + bg1.z, 0.f); o1.w = fmaxf(acc[7] + bg1.w, 0.f);
    float4* op = (float4*)(agg + (size_t)node * 512) + lane * 2;
    op[0] = o0; op[1] = o1;
}

// ---------------------------------------------------------------- batch segment bounds (batch sorted)
__global__ void k_bounds(const int* __restrict__ batch, int* __restrict__ segstart, int n, int b) {
    int i = blockIdx.x * 256 + threadIdx.x;
    if (i > b) return;
    int lo = 0, hi = n;
    while (lo < hi) { int mid = (lo + hi) >> 1; if (batch[mid] < i) lo = mid + 1; else hi = mid; }
    segstart[i] = lo;
}

// ---------------------------------------------------------------- Set2Set LSTM step (block per batch row)
__global__ void k_lstm(const float* __restrict__ W_ih, const float* __restrict__ W_hh,
                       const float* __restrict__ b_ih, const float* __restrict__ b_hh,
                       const float* __restrict__ r_in, float* __restrict__ h, float* __restrict__ c) {
    int b = blockIdx.x;
    int g = threadIdx.x;   // 0..255 (gate index)
    __shared__ float gs[256];
    __shared__ float hs[64], rs_[64];
    if (g < 64) hs[g] = h[(size_t)b * 64 + g];
    else if (g < 128) rs_[g - 64] = r_in[(size_t)b * 64 + (g - 64)];
    __syncthreads();
    float acc = b_ih[g] + b_hh[g];
    const float* wi = W_ih + (size_t)g * 128;
    const float* wh = W_hh + (size_t)g * 64;
    #pragma unroll 8
    for (int k = 0; k < 64; k++) acc += hs[k] * (wi[k] + wh[k]) + rs_[k] * wi[64 + k];
    gs[g] = acc;
    __syncthreads();
    if (g < 64) {
        float ig = gs[g], fg = gs[64 + g], gg = gs[128 + g], og = gs[192 + g];
        float cc = c[(size_t)b * 64 + g];
        float si = 1.f / (1.f + __expf(-ig));
        float sf = 1.f / (1.f + __expf(-fg));
        float so = 1.f / (1.f + __expf(-og));
        float cn = sf * cc + si * tanhf(gg);
        c[(size_t)b * 64 + g] = cn;
        h[(size_t)b * 64 + g] = so * tanhf(cn);
    }
}

__global__ void k_e2(const float* __restrict__ out2, const float* __restrict__ h,
                     const int* __restrict__ batch, float* __restrict__ e2, int n) {
    int i = blockIdx.x * 256 + threadIdx.x;
    if (i >= n) return;
    int b = batch[i];
    const float4* op = (const float4*)(out2 + (size_t)i * 64);
    const float4* hp = (const float4*)(h + (size_t)b * 64);
    float s = 0.f;
    #pragma unroll
    for (int j = 0; j < 16; j++) {
        float4 o = op[j], hv = hp[j];
        s += o.x * hv.x + o.y * hv.y + o.z * hv.z + o.w * hv.w;
    }
    e2[i] = s;
}

__global__ void k_seg(const float* __restrict__ e2, const int* __restrict__ segstart,
                      float* __restrict__ m2, float* __restrict__ s2) {
    int b = blockIdx.x, t = threadIdx.x;   // 64 threads
    int beg = segstart[b], end = segstart[b + 1];
    float m = -1e30f;
    for (int i = beg + t; i < end; i += 64) m = fmaxf(m, e2[i]);
    #pragma unroll
    for (int off = 32; off > 0; off >>= 1) m = fmaxf(m, __shfl_xor(m, off));
    float s = 0.f;
    for (int i = beg + t; i < end; i += 64) s += __expf(e2[i] - m);
    #pragma unroll
    for (int off = 32; off > 0; off >>= 1) s += __shfl_xor(s, off);
    if (t == 0) { m2[b] = m; s2[b] = s; }
}

__global__ void k_r(const float* __restrict__ e2, const float* __restrict__ out2,
                    const int* __restrict__ segstart, const float* __restrict__ m2,
                    const float* __restrict__ s2, float* __restrict__ r_out) {
    int b = blockIdx.x;
    int tid = threadIdx.x;           // 256 threads = 4 waves
    int d = tid & 63, w = tid >> 6;
    __shared__ float part[4][64];
    int beg = segstart[b], end = segstart[b + 1];
    float m = m2[b], sv = s2[b];
    float inv = sv > 0.f ? 1.f / sv : 0.f;
    float acc = 0.f;
    for (int i = beg + w; i < end; i += 4)
        acc += __expf(e2[i] - m) * out2[(size_t)i * 64 + d];
    part[w][d] = acc;
    __syncthreads();
    if (w == 0)
        r_out[(size_t)b * 64 + d] = (part[0][d] + part[1][d] + part[2][d] + part[3][d]) * inv;
}

__global__ void k_final(const float* __restrict__ h, const float* __restrict__ r,
                        const float* __restrict__ W1, const float* __restrict__ b1,
                        const float* __restrict__ W2, const float* __restrict__ b2,
                        float* __restrict__ out) {
    int b = blockIdx.x, j = threadIdx.x;  // 64 threads
    float t = b1[j];
    const float* hb = h + (size_t)b * 64;
    const float* rb = r + (size_t)b * 64;
    #pragma unroll 8
    for (int k = 0; k < 64; k++)
        t += hb[k] * W1[(size_t)k * 64 + j] + rb[k] * W1[(size_t)(64 + k) * 64 + j];
    t = fmaxf(t, 0.f) * W2[j];
    #pragma unroll
    for (int off = 32; off > 0; off >>= 1) t += __shfl_xor(t, off);
    if (j == 0) out[b] = t + b2[0];
}

// ----------------------------------------------------------------
extern "C" void kernel_launch(void* const* d_in, const int* in_sizes, int n_in,
                              void* d_out, int out_size, void* d_ws, size_t ws_size,
                              hipStream_t stream) {
    const float* x     = (const float*)d_in[0];
    const int*   ei    = (const int*)d_in[1];
    const int*   batch = (const int*)d_in[2];
    const float* W0    = (const float*)d_in[3];
    const float* b0    = (const float*)d_in[4];
    const float* Wg    = (const float*)d_in[5];
    const float* att_s = (const float*)d_in[6];
    const float* att_d = (const float*)d_in[7];
    const float* bg    = (const float*)d_in[8];
    const float* Wh    = (const float*)d_in[9];
    const float* bh    = (const float*)d_in[10];
    const float* W_ih  = (const float*)d_in[11];
    const float* W_hh  = (const float*)d_in[12];
    const float* b_ih  = (const float*)d_in[13];
    const float* b_hh  = (const float*)d_in[14];
    const float* W1    = (const float*)d_in[15];
    const float* b1    = (const float*)d_in[16];
    const float* W2    = (const float*)d_in[17];
    const float* b2    = (const float*)d_in[18];
    float* out = (float*)d_out;

    const int* esrc = ei;
    const int* edst = ei + N_EDGES;

    char* wsb = (char*)d_ws;
    size_t off = 0;
    auto alloc = [&](size_t bytes) {
        void* p = wsb + off;
        off = (off + bytes + 255) & ~(size_t)255;
        return p;
    };
    float* h0     = (float*)alloc((size_t)N_NODES * 64 * 4);
    float* xh     = (float*)alloc((size_t)N_NODES * 512 * 4);
    float* a_s    = (float*)alloc((size_t)N_NODES * 8 * 4);
    float* a_d    = (float*)alloc((size_t)N_NODES * 8 * 4);
    float* agg    = (float*)alloc((size_t)N_NODES * 512 * 4);
    float* out2   = (float*)alloc((size_t)N_NODES * 64 * 4);
    float* e2     = (float*)alloc((size_t)N_NODES * 4);
    int*   deg    = (int*)alloc((size_t)N_NODES * 4);
    int*   offs   = (int*)alloc((size_t)(N_NODES + 1) * 4);
    int*   cursor = (int*)alloc((size_t)N_NODES * 4);
    int*   adj    = (int*)alloc((size_t)(N_EDGES + N_NODES) * 4);
    int*   segst  = (int*)alloc((size_t)(NBATCH + 1) * 4);
    float* m2     = (float*)alloc((size_t)NBATCH * 4);
    float* s2     = (float*)alloc((size_t)NBATCH * 4);
    float* hstate = (float*)alloc((size_t)NBATCH * 64 * 4);
    float* cstate = (float*)alloc((size_t)NBATCH * 64 * 4);
    float* r0     = (float*)alloc((size_t)NBATCH * 64 * 4);
    float* r1     = (float*)alloc((size_t)NBATCH * 64 * 4);

    // split-K partial buffer: reuse xh region (xh dead after k_gat); 4*20000*64*4 = 20.5 MB <= 41 MB
    float* part = xh;

    // init
    hipMemsetAsync(deg, 0, (size_t)N_NODES * 4, stream);
    hipMemsetAsync(hstate, 0, (size_t)NBATCH * 64 * 4, stream);
    hipMemsetAsync(cstate, 0, (size_t)NBATCH * 64 * 4, stream);
    hipMemsetAsync(r0, 0, (size_t)NBATCH * 64 * 4, stream);

    // node MLP + GAT projection
    k_h0<<<(N_NODES + 3) / 4, 256, 0, stream>>>(x, W0, b0, h0, N_NODES);
    // xh = h0 @ Wg : K=64, N=512
    k_gemm<64, 512, 1, false><<<dim3(((N_NODES + 63) / 64) * 8, 1), 256, 0, stream>>>(h0, Wg, xh, N_NODES);
    k_att<<<(N_NODES * 8 + 255) / 256, 256, 0, stream>>>(xh, att_s, att_d, a_s, a_d, N_NODES);

    // CSR by dst (with self loops)
    k_count<<<(N_EDGES + 255) / 256, 256, 0, stream>>>(edst, deg, N_EDGES);
    k_scan<<<1, 1024, 0, stream>>>(deg, offs, N_NODES);
    k_fill_self<<<(N_NODES + 255) / 256, 256, 0, stream>>>(offs, adj, cursor, N_NODES);
    k_fill_edge<<<(N_EDGES + 255) / 256, 256, 0, stream>>>(esrc, edst, cursor, adj, N_EDGES);

    // GAT aggregate + head_nn
    k_gat<<<(N_NODES + 3) / 4, 256, 0, stream>>>(offs, adj, a_s, a_d, xh, bg, agg, N_NODES);
    // out2 = relu(agg @ Wh + bh) : K=512, N=64, split-K=4 (partials into dead xh region)
    k_gemm<512, 64, 4, true><<<dim3((N_NODES + 63) / 64, 4), 256, 0, stream>>>(agg, Wh, part, N_NODES);
    k_reduce4<<<(N_NODES * 16 + 255) / 256, 256, 0, stream>>>(part, bh, out2, N_NODES);

    // Set2Set
    k_bounds<<<1, 256, 0, stream>>>(batch, segst, N_NODES, NBATCH);
    float* rin = r0;
    float* rout = r1;
    for (int it = 0; it < 3; it++) {
        k_lstm<<<NBATCH, 256, 0, stream>>>(W_ih, W_hh, b_ih, b_hh, rin, hstate, cstate);
        k_e2<<<(N_NODES + 255) / 256, 256, 0, stream>>>(out2, hstate, batch, e2, N_NODES);
        k_seg<<<NBATCH, 64, 0, stream>>>(e2, segst, m2, s2);
        k_r<<<NBATCH, 256, 0, stream>>>(e2, out2, segst, m2, s2, rout);
        float* tmp = rin; rin = rout; rout = tmp;
    }
    k_final<<<NBATCH, 64, 0, stream>>>(hstate, rin, W1, b1, W2, b2, out);
}

// Round 3
// 377.368 us; speedup vs baseline: 1.5947x; 1.1092x over previous
//
#include <hip/hip_runtime.h>

#define N_NODES 20000
#define N_EDGES 320000
#define NBATCH  128

// ---------------------------------------------------------------- h0 = relu(x@W0+b0)
__global__ void k_h0(const float* __restrict__ x, const float* __restrict__ W0,
                     const float* __restrict__ b0, float* __restrict__ h0, int n) {
    __shared__ float ws[25 * 64];
    __shared__ float bs[64];
    int t = threadIdx.x;
    for (int i = t; i < 25 * 64; i += 256) ws[i] = W0[i];
    if (t < 64) bs[t] = b0[t];
    __syncthreads();
    int node = blockIdx.x * 4 + (t >> 6);
    int c = t & 63;
    if (node >= n) return;
    float s = bs[c];
    const float* xr = x + (size_t)node * 25;
    #pragma unroll
    for (int k = 0; k < 25; k++) s += xr[k] * ws[k * 64 + c];
    h0[(size_t)node * 64 + c] = fmaxf(s, 0.f);
}

// ---------------------------------------------------------------- vsd[k][o]: o<8 -> Wg_h @ att_s_h, o>=8 -> @ att_d_h
__global__ void k_vsd(const float* __restrict__ Wg, const float* __restrict__ att_s,
                      const float* __restrict__ att_d, float* __restrict__ vsd) {
    int t = threadIdx.x;  // 512 threads: t -> (k, h)
    int k = t >> 3, h = t & 7;
    const float* wrow = Wg + (size_t)k * 512 + h * 64;
    float s1 = 0.f, s2 = 0.f;
    #pragma unroll 8
    for (int c = 0; c < 64; c++) {
        float w = wrow[c];
        s1 += w * att_s[h * 64 + c];
        s2 += w * att_d[h * 64 + c];
    }
    vsd[k * 16 + h] = s1;
    vsd[k * 16 + 8 + h] = s2;
}

// ---------------------------------------------------------------- [a_s|a_d] = h0 @ vsd  (K=64, N=16)
__global__ __launch_bounds__(256) void k_asd(const float* __restrict__ h0,
                                             const float* __restrict__ vsd,
                                             float* __restrict__ a_s, float* __restrict__ a_d) {
    __shared__ float hs[16][65];
    __shared__ float vl[64 * 16];
    int tid = threadIdx.x;
    int rbase = blockIdx.x * 16;
    {
        int row = tid / 16, c4 = (tid % 16) * 4;
        float4 hv = *(const float4*)(h0 + (size_t)(rbase + row) * 64 + c4);
        hs[row][c4] = hv.x; hs[row][c4 + 1] = hv.y; hs[row][c4 + 2] = hv.z; hs[row][c4 + 3] = hv.w;
    }
    #pragma unroll
    for (int j = 0; j < 4; j++) vl[tid + j * 256] = vsd[tid + j * 256];
    __syncthreads();
    int nl = tid / 16, o = tid % 16;
    float acc = 0.f;
    #pragma unroll 16
    for (int k = 0; k < 64; k++) acc += hs[nl][k] * vl[k * 16 + o];
    int node = rbase + nl;
    if (o < 8) a_s[node * 8 + o] = acc;
    else       a_d[node * 8 + (o - 8)] = acc;
}

// ---------------------------------------------------------------- CSR build
__global__ void k_count(const int* __restrict__ dst, int* __restrict__ deg, int e) {
    int i = blockIdx.x * 256 + threadIdx.x;
    if (i < e) atomicAdd(&deg[dst[i]], 1);
}

__global__ __launch_bounds__(1024) void k_scan1(const int* __restrict__ deg,
                                                int* __restrict__ tmp, int* __restrict__ bsum, int n) {
    __shared__ int wsum[16];
    int tid = threadIdx.x, lane = tid & 63, w = tid >> 6;
    int i = blockIdx.x * 1024 + tid;
    int v = (i < n) ? deg[i] + 1 : 0;   // +1 self loop
    int x = v;
    #pragma unroll
    for (int off = 1; off < 64; off <<= 1) {
        int t = __shfl_up(x, off);
        if (lane >= off) x += t;
    }
    if (lane == 63) wsum[w] = x;
    __syncthreads();
    int pre = 0;
    #pragma unroll
    for (int j = 0; j < 16; j++) if (j < w) pre += wsum[j];
    if (i < n) tmp[i] = pre + x - v;    // block-local exclusive
    if (tid == 1023) bsum[blockIdx.x] = pre + x;
}

__global__ void k_scan2(const int* __restrict__ tmp, const int* __restrict__ bsum,
                        const int* __restrict__ deg, int* __restrict__ offs,
                        int* __restrict__ adj, int* __restrict__ cursor, int n, int nblk) {
    int i = blockIdx.x * 256 + threadIdx.x;
    if (i > n) return;
    int b = i >> 10;
    int pre = 0;
    for (int j = 0; j < b; j++) pre += bsum[j];
    if (i == n) {
        int tot = pre;
        for (int j = b; j < nblk; j++) tot += bsum[j];
        offs[n] = tot;
        return;
    }
    int o = pre + tmp[i];
    offs[i] = o;
    adj[o] = i;          // self loop first
    cursor[i] = o + 1;
}

__global__ void k_fill_edge(const int* __restrict__ src, const int* __restrict__ dst,
                            int* __restrict__ cursor, int* __restrict__ adj, int e) {
    int i = blockIdx.x * 256 + threadIdx.x;
    if (i >= e) return;
    int p = atomicAdd(&cursor[dst[i]], 1);
    adj[p] = src[i];
}

// ---------------------------------------------------------------- GAT: softmax + aggregate h0 rows (1 wave/node)
// agg_pre[node, h, k] = sum_src alpha_h(src,node) * h0[src, k]
__global__ __launch_bounds__(256) void k_gat2(const int* __restrict__ offs, const int* __restrict__ adj,
                                              const float* __restrict__ a_s, const float* __restrict__ a_d,
                                              const float* __restrict__ h0, float* __restrict__ agg_pre, int n) {
    int lane = threadIdx.x & 63;
    int node = blockIdx.x * 4 + (threadIdx.x >> 6);
    if (node >= n) return;
    int beg = offs[node], end = offs[node + 1];
    int h = lane & 7, g = lane >> 3;
    float ad = a_d[node * 8 + h];

    // pass 1: online (max,sum) per head; lane = g*8+h handles edges beg+g, beg+g+8, ...
    float m = -1e30f, s = 0.f;
    for (int i = beg + g; i < end; i += 8) {
        int src = adj[i];
        float e = a_s[src * 8 + h] + ad;
        e = e > 0.f ? e : 0.2f * e;
        if (e > m) { s = s * __expf(m - e) + 1.f; m = e; }
        else       { s += __expf(e - m); }
    }
    #pragma unroll
    for (int off = 8; off < 64; off <<= 1) {
        float mo = __shfl_xor(m, off), so = __shfl_xor(s, off);
        float mn = fmaxf(m, mo);
        s = s * __expf(m - mn) + so * __expf(mo - mn);
        m = mn;
    }
    float rcp = 1.f / s;   // this lane's head-h stats (replicated across g)

    // pass 2: chunks of 8 edges; lane (g,h) computes alpha for edge g head h, broadcast via shfl
    float acc[8] = {0.f, 0.f, 0.f, 0.f, 0.f, 0.f, 0.f, 0.f};
    for (int base = beg; base < end; base += 8) {
        int cnt = end - base; if (cnt > 8) cnt = 8;
        float alpha = 0.f; int srcv = 0;
        if (g < cnt) {
            srcv = adj[base + g];
            float e = a_s[srcv * 8 + h] + ad;
            e = e > 0.f ? e : 0.2f * e;
            alpha = __expf(e - m) * rcp;
        }
        int sg[8];
        #pragma unroll
        for (int g2 = 0; g2 < 8; g2++) sg[g2] = __shfl(srcv, g2 * 8);
        float xv[8];
        #pragma unroll
        for (int g2 = 0; g2 < 8; g2++)
            xv[g2] = (g2 < cnt) ? h0[(size_t)sg[g2] * 64 + lane] : 0.f;
        #pragma unroll
        for (int g2 = 0; g2 < 8; g2++) {
            #pragma unroll
            for (int h2 = 0; h2 < 8; h2++) {
                float av = __shfl(alpha, g2 * 8 + h2);
                acc[h2] += av * xv[g2];
            }
        }
    }
    #pragma unroll
    for (int h2 = 0; h2 < 8; h2++)
        agg_pre[(size_t)node * 512 + h2 * 64 + lane] = acc[h2];
}

// ---------------------------------------------------------------- agg[:, h*64+c] = relu(agg_pre[:,h,:] @ Wg_h + bg)
__global__ __launch_bounds__(256) void k_gemm_head(const float* __restrict__ A,
                                                   const float* __restrict__ Wg,
                                                   const float* __restrict__ bg,
                                                   float* __restrict__ C, int M) {
    __shared__ float As[32 * 65];
    __shared__ float Bs[32 * 64];
    int tid = threadIdx.x;
    int rbase = blockIdx.x * 64;
    int hh = blockIdx.y;
    int tx = tid % 16, ty = tid / 16;
    int la_r = tid / 8, la_k = (tid % 8) * 4;
    int lb_k = tid / 16, lb_c = (tid % 16) * 4;
    float acc[4][4] = {};
    for (int kg = 0; kg < 64; kg += 32) {
        #pragma unroll
        for (int rr = 0; rr < 2; rr++) {
            int r = rbase + la_r + rr * 32;
            float4 av = make_float4(0.f, 0.f, 0.f, 0.f);
            if (r < M) av = *(const float4*)(A + (size_t)r * 512 + hh * 64 + kg + la_k);
            int mm = la_r + rr * 32;
            As[(la_k + 0) * 65 + mm] = av.x;
            As[(la_k + 1) * 65 + mm] = av.y;
            As[(la_k + 2) * 65 + mm] = av.z;
            As[(la_k + 3) * 65 + mm] = av.w;
        }
        #pragma unroll
        for (int kk = 0; kk < 2; kk++) {
            int krow = lb_k + kk * 16;
            *(float4*)&Bs[krow * 64 + lb_c] =
                *(const float4*)(Wg + (size_t)(kg + krow) * 512 + hh * 64 + lb_c);
        }
        __syncthreads();
        #pragma unroll
        for (int k = 0; k < 32; k++) {
            float a0 = As[k * 65 + ty * 4 + 0];
            float a1 = As[k * 65 + ty * 4 + 1];
            float a2 = As[k * 65 + ty * 4 + 2];
            float a3 = As[k * 65 + ty * 4 + 3];
            float4 b = *(const float4*)&Bs[k * 64 + tx * 4];
            acc[0][0] += a0 * b.x; acc[0][1] += a0 * b.y; acc[0][2] += a0 * b.z; acc[0][3] += a0 * b.w;
            acc[1][0] += a1 * b.x; acc[1][1] += a1 * b.y; acc[1][2] += a1 * b.z; acc[1][3] += a1 * b.w;
            acc[2][0] += a2 * b.x; acc[2][1] += a2 * b.y; acc[2][2] += a2 * b.z; acc[2][3] += a2 * b.w;
            acc[3][0] += a3 * b.x; acc[3][1] += a3 * b.y; acc[3][2] += a3 * b.z; acc[3][3] += a3 * b.w;
        }
        __syncthreads();
    }
    float4 bgv = *(const float4*)(bg + hh * 64 + tx * 4);
    #pragma unroll
    for (int i = 0; i < 4; i++) {
        int r = rbase + ty * 4 + i;
        if (r >= M) continue;
        float4 o;
        o.x = fmaxf(acc[i][0] + bgv.x, 0.f);
        o.y = fmaxf(acc[i][1] + bgv.y, 0.f);
        o.z = fmaxf(acc[i][2] + bgv.z, 0.f);
        o.w = fmaxf(acc[i][3] + bgv.w, 0.f);
        *(float4*)(C + (size_t)r * 512 + hh * 64 + tx * 4) = o;
    }
}

// ---------------------------------------------------------------- tiled GEMM (split-K partials): C = A[M,512] @ W[512,64]
template <int K, int N, int KSPLIT>
__global__ __launch_bounds__(256) void k_gemm(const float* __restrict__ A,
                                              const float* __restrict__ W,
                                              float* __restrict__ C, int M) {
    constexpr int KS = K / KSPLIT;
    __shared__ float As[32 * 65];
    __shared__ float Bs[32 * 64];
    int tid = threadIdx.x;
    int rbase = blockIdx.x * 64;
    int kbase0 = blockIdx.y * KS;
    int tx = tid % 16, ty = tid / 16;
    int la_r = tid / 8, la_k = (tid % 8) * 4;
    int lb_k = tid / 16, lb_c = (tid % 16) * 4;
    float acc[4][4] = {};
    for (int kc = 0; kc < KS; kc += 32) {
        int kg = kbase0 + kc;
        #pragma unroll
        for (int rr = 0; rr < 2; rr++) {
            int r = rbase + la_r + rr * 32;
            float4 av = make_float4(0.f, 0.f, 0.f, 0.f);
            if (r < M) av = *(const float4*)(A + (size_t)r * K + kg + la_k);
            int mm = la_r + rr * 32;
            As[(la_k + 0) * 65 + mm] = av.x;
            As[(la_k + 1) * 65 + mm] = av.y;
            As[(la_k + 2) * 65 + mm] = av.z;
            As[(la_k + 3) * 65 + mm] = av.w;
        }
        #pragma unroll
        for (int kk = 0; kk < 2; kk++) {
            int krow = lb_k + kk * 16;
            *(float4*)&Bs[krow * 64 + lb_c] =
                *(const float4*)(W + (size_t)(kg + krow) * N + lb_c);
        }
        __syncthreads();
        #pragma unroll
        for (int k = 0; k < 32; k++) {
            float a0 = As[k * 65 + ty * 4 + 0];
            float a1 = As[k * 65 + ty * 4 + 1];
            float a2 = As[k * 65 + ty * 4 + 2];
            float a3 = As[k * 65 + ty * 4 + 3];
            float4 b = *(const float4*)&Bs[k * 64 + tx * 4];
            acc[0][0] += a0 * b.x; acc[0][1] += a0 * b.y; acc[0][2] += a0 * b.z; acc[0][3] += a0 * b.w;
            acc[1][0] += a1 * b.x; acc[1][1] += a1 * b.y; acc[1][2] += a1 * b.z; acc[1][3] += a1 * b.w;
            acc[2][0] += a2 * b.x; acc[2][1] += a2 * b.y; acc[2][2] += a2 * b.z; acc[2][3] += a2 * b.w;
            acc[3][0] += a3 * b.x; acc[3][1] += a3 * b.y; acc[3][2] += a3 * b.z; acc[3][3] += a3 * b.w;
        }
        __syncthreads();
    }
    float* Cb = C + (size_t)blockIdx.y * M * N;
    #pragma unroll
    for (int i = 0; i < 4; i++) {
        int r = rbase + ty * 4 + i;
        if (r >= M) continue;
        float4 o;
        o.x = acc[i][0]; o.y = acc[i][1]; o.z = acc[i][2]; o.w = acc[i][3];
        *(float4*)(Cb + (size_t)r * N + tx * 4) = o;
    }
}

__global__ void k_reduce4(const float* __restrict__ part, const float* __restrict__ bias,
                          float* __restrict__ out, int M) {
    int idx = blockIdx.x * 256 + threadIdx.x;
    if (idx >= M * 16) return;
    int r = idx / 16, cq = idx % 16;
    float4 s = make_float4(0.f, 0.f, 0.f, 0.f);
    #pragma unroll
    for (int y = 0; y < 4; y++) {
        float4 p = *(const float4*)(part + ((size_t)y * M + r) * 64 + cq * 4);
        s.x += p.x; s.y += p.y; s.z += p.z; s.w += p.w;
    }
    float4 b = *(const float4*)(bias + cq * 4);
    s.x = fmaxf(s.x + b.x, 0.f); s.y = fmaxf(s.y + b.y, 0.f);
    s.z = fmaxf(s.z + b.z, 0.f); s.w = fmaxf(s.w + b.w, 0.f);
    *(float4*)(out + (size_t)r * 64 + cq * 4) = s;
}

// ---------------------------------------------------------------- batch segment bounds (batch sorted)
__global__ void k_bounds(const int* __restrict__ batch, int* __restrict__ segstart, int n, int b) {
    int i = blockIdx.x * 256 + threadIdx.x;
    if (i > b) return;
    int lo = 0, hi = n;
    while (lo < hi) { int mid = (lo + hi) >> 1; if (batch[mid] < i) lo = mid + 1; else hi = mid; }
    segstart[i] = lo;
}

// ---------------------------------------------------------------- Set2Set LSTM step
__global__ void k_lstm(const float* __restrict__ W_ih, const float* __restrict__ W_hh,
                       const float* __restrict__ b_ih, const float* __restrict__ b_hh,
                       const float* __restrict__ r_in, float* __restrict__ h, float* __restrict__ c) {
    int b = blockIdx.x;
    int g = threadIdx.x;
    __shared__ float gs[256];
    __shared__ float hs[64], rs_[64];
    if (g < 64) hs[g] = h[(size_t)b * 64 + g];
    else if (g < 128) rs_[g - 64] = r_in[(size_t)b * 64 + (g - 64)];
    __syncthreads();
    float acc = b_ih[g] + b_hh[g];
    const float* wi = W_ih + (size_t)g * 128;
    const float* wh = W_hh + (size_t)g * 64;
    #pragma unroll 8
    for (int k = 0; k < 64; k++) acc += hs[k] * (wi[k] + wh[k]) + rs_[k] * wi[64 + k];
    gs[g] = acc;
    __syncthreads();
    if (g < 64) {
        float ig = gs[g], fg = gs[64 + g], gg = gs[128 + g], og = gs[192 + g];
        float cc = c[(size_t)b * 64 + g];
        float si = 1.f / (1.f + __expf(-ig));
        float sf = 1.f / (1.f + __expf(-fg));
        float so = 1.f / (1.f + __expf(-og));
        float cn = sf * cc + si * tanhf(gg);
        c[(size_t)b * 64 + g] = cn;
        h[(size_t)b * 64 + g] = so * tanhf(cn);
    }
}

// ---------------------------------------------------------------- fused e2 + segment softmax + weighted reduce
__global__ __launch_bounds__(256) void k_segr(const float* __restrict__ out2,
                                              const float* __restrict__ hstate,
                                              const int* __restrict__ segst,
                                              float* __restrict__ e2, float* __restrict__ r_out) {
    int b = blockIdx.x, tid = threadIdx.x, lane = tid & 63, w = tid >> 6;
    __shared__ float hl[64];
    __shared__ float red[4];
    __shared__ float part[4][64];
    int beg = segst[b], end = segst[b + 1];
    if (tid < 64) hl[tid] = hstate[(size_t)b * 64 + tid];
    __syncthreads();
    float hv = hl[lane];
    // phase A: e2[i] = dot(out2[i], h[b]); wave-per-row; track max
    float mloc = -1e30f;
    for (int i = beg + w; i < end; i += 4) {
        float d = out2[(size_t)i * 64 + lane] * hv;
        #pragma unroll
        for (int off = 1; off < 64; off <<= 1) d += __shfl_xor(d, off);
        if (lane == 0) e2[i] = d;
        mloc = fmaxf(mloc, d);
    }
    if (lane == 0) red[w] = mloc;
    __threadfence_block();
    __syncthreads();
    float m = fmaxf(fmaxf(red[0], red[1]), fmaxf(red[2], red[3]));
    __syncthreads();
    // phase B: sum of exp
    float sloc = 0.f;
    for (int i = beg + tid; i < end; i += 256) sloc += __expf(e2[i] - m);
    #pragma unroll
    for (int off = 1; off < 64; off <<= 1) sloc += __shfl_xor(sloc, off);
    if (lane == 0) red[w] = sloc;
    __syncthreads();
    float sv = red[0] + red[1] + red[2] + red[3];
    float inv = sv > 0.f ? 1.f / sv : 0.f;
    // phase C: r = sum alpha * out2
    float acc = 0.f;
    for (int i = beg + w; i < end; i += 4)
        acc += __expf(e2[i] - m) * out2[(size_t)i * 64 + lane];
    part[w][lane] = acc;
    __syncthreads();
    if (w == 0)
        r_out[(size_t)b * 64 + lane] =
            (part[0][lane] + part[1][lane] + part[2][lane] + part[3][lane]) * inv;
}

__global__ void k_final(const float* __restrict__ h, const float* __restrict__ r,
                        const float* __restrict__ W1, const float* __restrict__ b1,
                        const float* __restrict__ W2, const float* __restrict__ b2,
                        float* __restrict__ out) {
    int b = blockIdx.x, j = threadIdx.x;
    float t = b1[j];
    const float* hb = h + (size_t)b * 64;
    const float* rb = r + (size_t)b * 64;
    #pragma unroll 8
    for (int k = 0; k < 64; k++)
        t += hb[k] * W1[(size_t)k * 64 + j] + rb[k] * W1[(size_t)(64 + k) * 64 + j];
    t = fmaxf(t, 0.f) * W2[j];
    #pragma unroll
    for (int off = 32; off > 0; off >>= 1) t += __shfl_xor(t, off);
    if (j == 0) out[b] = t + b2[0];
}

// ----------------------------------------------------------------
extern "C" void kernel_launch(void* const* d_in, const int* in_sizes, int n_in,
                              void* d_out, int out_size, void* d_ws, size_t ws_size,
                              hipStream_t stream) {
    const float* x     = (const float*)d_in[0];
    const int*   ei    = (const int*)d_in[1];
    const int*   batch = (const int*)d_in[2];
    const float* W0    = (const float*)d_in[3];
    const float* b0    = (const float*)d_in[4];
    const float* Wg    = (const float*)d_in[5];
    const float* att_s = (const float*)d_in[6];
    const float* att_d = (const float*)d_in[7];
    const float* bg    = (const float*)d_in[8];
    const float* Wh    = (const float*)d_in[9];
    const float* bh    = (const float*)d_in[10];
    const float* W_ih  = (const float*)d_in[11];
    const float* W_hh  = (const float*)d_in[12];
    const float* b_ih  = (const float*)d_in[13];
    const float* b_hh  = (const float*)d_in[14];
    const float* W1    = (const float*)d_in[15];
    const float* b1    = (const float*)d_in[16];
    const float* W2    = (const float*)d_in[17];
    const float* b2    = (const float*)d_in[18];
    float* out = (float*)d_out;

    const int* esrc = ei;
    const int* edst = ei + N_EDGES;

    char* wsb = (char*)d_ws;
    size_t off = 0;
    auto alloc = [&](size_t bytes) {
        void* p = wsb + off;
        off = (off + bytes + 255) & ~(size_t)255;
        return p;
    };
    float* h0      = (float*)alloc((size_t)N_NODES * 64 * 4);
    float* agg_pre = (float*)alloc((size_t)N_NODES * 512 * 4);
    float* agg     = (float*)alloc((size_t)N_NODES * 512 * 4);
    float* out2    = (float*)alloc((size_t)N_NODES * 64 * 4);
    float* e2      = (float*)alloc((size_t)N_NODES * 4);
    float* a_s     = (float*)alloc((size_t)N_NODES * 8 * 4);
    float* a_d     = (float*)alloc((size_t)N_NODES * 8 * 4);
    float* vsd     = (float*)alloc(64 * 16 * 4);
    int*   deg     = (int*)alloc((size_t)N_NODES * 4);
    int*   tmp     = (int*)alloc((size_t)N_NODES * 4);
    int*   bsum    = (int*)alloc(32 * 4);
    int*   offs    = (int*)alloc((size_t)(N_NODES + 1) * 4);
    int*   cursor  = (int*)alloc((size_t)N_NODES * 4);
    int*   adj     = (int*)alloc((size_t)(N_EDGES + N_NODES) * 4);
    int*   segst   = (int*)alloc((size_t)(NBATCH + 1) * 4);
    float* hstate  = (float*)alloc((size_t)NBATCH * 64 * 4);   // contiguous with cstate, r0
    float* cstate  = (float*)alloc((size_t)NBATCH * 64 * 4);
    float* r0      = (float*)alloc((size_t)NBATCH * 64 * 4);
    float* r1      = (float*)alloc((size_t)NBATCH * 64 * 4);

    float* part = agg_pre;   // reuse: agg_pre dead after k_gemm_head

    hipMemsetAsync(deg, 0, (size_t)N_NODES * 4, stream);
    hipMemsetAsync(hstate, 0, (size_t)3 * NBATCH * 64 * 4, stream);  // h, c, r0

    k_h0<<<(N_NODES + 3) / 4, 256, 0, stream>>>(x, W0, b0, h0, N_NODES);
    k_vsd<<<1, 512, 0, stream>>>(Wg, att_s, att_d, vsd);
    k_asd<<<N_NODES / 16, 256, 0, stream>>>(h0, vsd, a_s, a_d);

    k_count<<<(N_EDGES + 255) / 256, 256, 0, stream>>>(edst, deg, N_EDGES);
    const int nblk = (N_NODES + 1023) / 1024;
    k_scan1<<<nblk, 1024, 0, stream>>>(deg, tmp, bsum, N_NODES);
    k_scan2<<<(N_NODES + 256) / 256, 256, 0, stream>>>(tmp, bsum, deg, offs, adj, cursor, N_NODES, nblk);
    k_fill_edge<<<(N_EDGES + 255) / 256, 256, 0, stream>>>(esrc, edst, cursor, adj, N_EDGES);
    k_bounds<<<1, 256, 0, stream>>>(batch, segst, N_NODES, NBATCH);

    k_gat2<<<(N_NODES + 3) / 4, 256, 0, stream>>>(offs, adj, a_s, a_d, h0, agg_pre, N_NODES);
    k_gemm_head<<<dim3((N_NODES + 63) / 64, 8), 256, 0, stream>>>(agg_pre, Wg, bg, agg, N_NODES);
    k_gemm<512, 64, 4><<<dim3((N_NODES + 63) / 64, 4), 256, 0, stream>>>(agg, Wh, part, N_NODES);
    k_reduce4<<<(N_NODES * 16 + 255) / 256, 256, 0, stream>>>(part, bh, out2, N_NODES);

    float* rin = r0;
    float* rout = r1;
    for (int it = 0; it < 3; it++) {
        k_lstm<<<NBATCH, 256, 0, stream>>>(W_ih, W_hh, b_ih, b_hh, rin, hstate, cstate);
        k_segr<<<NBATCH, 256, 0, stream>>>(out2, hstate, segst, e2, rout);
        float* tmp2 = rin; rin = rout; rout = tmp2;
    }
    k_final<<<NBATCH, 64, 0, stream>>>(hstate, rin, W1, b1, W2, b2, out);
}

// Round 4
// 353.638 us; speedup vs baseline: 1.7017x; 1.0671x over previous
//
#include <hip/hip_runtime.h>

#define N_NODES 20000
#define N_EDGES 320000
#define NBATCH  128

// ---------------------------------------------------------------- h0 = relu(x@W0+b0); also zero deg
__global__ void k_h0(const float* __restrict__ x, const float* __restrict__ W0,
                     const float* __restrict__ b0, float* __restrict__ h0,
                     int* __restrict__ deg, int n) {
    __shared__ float ws[25 * 64];
    __shared__ float bs[64];
    __shared__ float xs[100];
    int t = threadIdx.x;
    int gid = blockIdx.x * 256 + t;
    if (gid < n) deg[gid] = 0;
    for (int i = t; i < 25 * 64; i += 256) ws[i] = W0[i];
    if (t < 64) bs[t] = b0[t];
    int nb = blockIdx.x * 4;
    if (t < 100 && nb * 25 + t < n * 25) xs[t] = x[(size_t)nb * 25 + t];
    __syncthreads();
    int node = nb + (t >> 6);
    int c = t & 63;
    if (node >= n) return;
    float s = bs[c];
    const float* xr = xs + (t >> 6) * 25;
    #pragma unroll
    for (int k = 0; k < 25; k++) s += xr[k] * ws[k * 64 + c];
    h0[(size_t)node * 64 + c] = fmaxf(s, 0.f);
}

// ---------------------------------------------------------------- merged tiny setup: vsd + segment bounds
__global__ void k_small(const float* __restrict__ Wg, const float* __restrict__ att_s,
                        const float* __restrict__ att_d, float* __restrict__ vsd,
                        const int* __restrict__ batch, int* __restrict__ segst, int n, int b) {
    int t = threadIdx.x;
    if (blockIdx.x == 0) {
        // vsd[k][o]: o<8 -> Wg_h @ att_s_h ; o>=8 -> @ att_d_h   (512 threads)
        int k = t >> 3, h = t & 7;
        const float* wrow = Wg + (size_t)k * 512 + h * 64;
        float s1 = 0.f, s2 = 0.f;
        #pragma unroll 8
        for (int c = 0; c < 64; c++) {
            float w = wrow[c];
            s1 += w * att_s[h * 64 + c];
            s2 += w * att_d[h * 64 + c];
        }
        vsd[k * 16 + h] = s1;
        vsd[k * 16 + 8 + h] = s2;
    } else {
        if (t > b) return;
        int lo = 0, hi = n;
        while (lo < hi) { int mid = (lo + hi) >> 1; if (batch[mid] < t) lo = mid + 1; else hi = mid; }
        segst[t] = lo;
    }
}

// ---------------------------------------------------------------- [a_s|a_d] = h0 @ vsd; also zero h/c/r0
__global__ __launch_bounds__(256) void k_asd(const float* __restrict__ h0,
                                             const float* __restrict__ vsd,
                                             float* __restrict__ a_s, float* __restrict__ a_d,
                                             float* __restrict__ hcr) {
    __shared__ float hs[16][65];
    __shared__ float vl[64 * 16];
    int tid = threadIdx.x;
    int gid = blockIdx.x * 256 + tid;
    if (gid < 3 * NBATCH * 64) hcr[gid] = 0.f;
    int rbase = blockIdx.x * 16;
    {
        int row = tid / 16, c4 = (tid % 16) * 4;
        float4 hv = *(const float4*)(h0 + (size_t)(rbase + row) * 64 + c4);
        hs[row][c4] = hv.x; hs[row][c4 + 1] = hv.y; hs[row][c4 + 2] = hv.z; hs[row][c4 + 3] = hv.w;
    }
    #pragma unroll
    for (int j = 0; j < 4; j++) vl[tid + j * 256] = vsd[tid + j * 256];
    __syncthreads();
    int nl = tid / 16, o = tid % 16;
    float acc = 0.f;
    #pragma unroll 16
    for (int k = 0; k < 64; k++) acc += hs[nl][k] * vl[k * 16 + o];
    int node = rbase + nl;
    if (o < 8) a_s[node * 8 + o] = acc;
    else       a_d[node * 8 + (o - 8)] = acc;
}

// ---------------------------------------------------------------- CSR build
__global__ void k_count(const int* __restrict__ dst, int* __restrict__ deg, int e) {
    int i = blockIdx.x * 256 + threadIdx.x;
    if (i < e) atomicAdd(&deg[dst[i]], 1);
}

__global__ __launch_bounds__(1024) void k_scan1(const int* __restrict__ deg,
                                                int* __restrict__ tmp, int* __restrict__ bsum, int n) {
    __shared__ int wsum[16];
    int tid = threadIdx.x, lane = tid & 63, w = tid >> 6;
    int i = blockIdx.x * 1024 + tid;
    int v = (i < n) ? deg[i] + 1 : 0;   // +1 self loop
    int x = v;
    #pragma unroll
    for (int off = 1; off < 64; off <<= 1) {
        int t = __shfl_up(x, off);
        if (lane >= off) x += t;
    }
    if (lane == 63) wsum[w] = x;
    __syncthreads();
    int pre = 0;
    #pragma unroll
    for (int j = 0; j < 16; j++) if (j < w) pre += wsum[j];
    if (i < n) tmp[i] = pre + x - v;    // block-local exclusive
    if (tid == 1023) bsum[blockIdx.x] = pre + x;
}

__global__ void k_scan2(const int* __restrict__ tmp, const int* __restrict__ bsum,
                        int* __restrict__ offs, int* __restrict__ adj,
                        int* __restrict__ cursor, int n, int nblk) {
    int i = blockIdx.x * 256 + threadIdx.x;
    if (i > n) return;
    int b = i >> 10;
    int pre = 0;
    for (int j = 0; j < b; j++) pre += bsum[j];
    if (i == n) {
        int tot = pre;
        for (int j = b; j < nblk; j++) tot += bsum[j];
        offs[n] = tot;
        return;
    }
    int o = pre + tmp[i];
    offs[i] = o;
    adj[o] = i;          // self loop first
    cursor[i] = o + 1;
}

__global__ void k_fill_edge(const int* __restrict__ src, const int* __restrict__ dst,
                            int* __restrict__ cursor, int* __restrict__ adj, int e) {
    int i = blockIdx.x * 256 + threadIdx.x;
    if (i >= e) return;
    int p = atomicAdd(&cursor[dst[i]], 1);
    adj[p] = src[i];
}

// ---------------------------------------------------------------- GAT: softmax + aggregate h0 (2 waves/node, 4 heads each)
__global__ __launch_bounds__(256) void k_gat2(const int* __restrict__ offs, const int* __restrict__ adj,
                                              const float* __restrict__ a_s, const float* __restrict__ a_d,
                                              const float* __restrict__ h0, float* __restrict__ agg_pre, int n) {
    int lane = threadIdx.x & 63;
    int wv = threadIdx.x >> 6;
    int node = blockIdx.x * 2 + (wv >> 1);
    if (node >= n) return;
    int hb = (wv & 1) * 4;             // this wave handles heads hb..hb+3
    int beg = offs[node], end = offs[node + 1];
    int h4 = lane & 3, g = lane >> 2;  // g = 0..15
    int head = hb + h4;
    float ad = a_d[node * 8 + head];

    // pass 1: online (max,sum); lane (g,h4) strides edges by 16
    float m = -1e30f, s = 0.f;
    for (int i = beg + g; i < end; i += 16) {
        int src = adj[i];
        float e = a_s[src * 8 + head] + ad;
        e = e > 0.f ? e : 0.2f * e;
        if (e > m) { s = s * __expf(m - e) + 1.f; m = e; }
        else       { s += __expf(e - m); }
    }
    #pragma unroll
    for (int off = 4; off < 64; off <<= 1) {
        float mo = __shfl_xor(m, off), so = __shfl_xor(s, off);
        float mn = fmaxf(m, mo);
        s = s * __expf(m - mn) + so * __expf(mo - mn);
        m = mn;
    }
    float rcp = 1.f / s;

    // pass 2: 16-edge chunks; lane (g,h4) computes alpha for edge g, head hb+h4
    float acc[4] = {0.f, 0.f, 0.f, 0.f};
    for (int base = beg; base < end; base += 16) {
        int cnt = end - base; if (cnt > 16) cnt = 16;
        float alpha = 0.f; int srcv = 0;
        if (g < cnt) {
            srcv = adj[base + g];
            float e = a_s[srcv * 8 + head] + ad;
            e = e > 0.f ? e : 0.2f * e;
            alpha = __expf(e - m) * rcp;
        }
        int sg[16];
        #pragma unroll
        for (int g2 = 0; g2 < 16; g2++) sg[g2] = __shfl(srcv, g2 * 4);
        float xv[16];
        #pragma unroll
        for (int g2 = 0; g2 < 16; g2++)
            xv[g2] = (g2 < cnt) ? h0[(size_t)sg[g2] * 64 + lane] : 0.f;
        #pragma unroll
        for (int g2 = 0; g2 < 16; g2++) {
            #pragma unroll
            for (int h2 = 0; h2 < 4; h2++) {
                float av = __shfl(alpha, g2 * 4 + h2);
                acc[h2] += av * xv[g2];
            }
        }
    }
    #pragma unroll
    for (int h2 = 0; h2 < 4; h2++)
        agg_pre[(size_t)node * 512 + (hb + h2) * 64 + lane] = acc[h2];
}

// ---------------------------------------------------------------- fused: out2 = relu( relu(agg_pre @h Wg + bg) @ Wh + bh )
// 32-row tiles; per head: GEMM1 (K=64) -> LDS -> accumulate GEMM2 (K=64)
__global__ __launch_bounds__(256) void k_fused(const float* __restrict__ agg_pre,
                                               const float* __restrict__ Wg,
                                               const float* __restrict__ bg,
                                               const float* __restrict__ Wh,
                                               const float* __restrict__ bh,
                                               float* __restrict__ out2) {
    __shared__ float As[64 * 33];   // A_h k-major: As[k*33 + r]
    __shared__ float Bs[64 * 64];   // Bs[k*64 + c]
    __shared__ float Cs[32 * 65];   // agg_h r-major: Cs[r*65 + k]
    int tid = threadIdx.x;
    int r0 = blockIdx.x * 32;
    int tx = tid % 16, ty = tid / 16;    // out tile: rows ty*2+i, cols tx*4+j
    float accO[2][4] = {};
    for (int h = 0; h < 8; h++) {
        {   // load A_h (32x64), transposed to k-major
            int rr = tid / 16, k4 = (tid % 16) * 4;
            #pragma unroll
            for (int pp = 0; pp < 2; pp++) {
                int r = rr + pp * 16;
                float4 av = *(const float4*)(agg_pre + (size_t)(r0 + r) * 512 + h * 64 + k4);
                As[(k4 + 0) * 33 + r] = av.x;
                As[(k4 + 1) * 33 + r] = av.y;
                As[(k4 + 2) * 33 + r] = av.z;
                As[(k4 + 3) * 33 + r] = av.w;
            }
        }
        {   // load Wg_h (64x64)
            int kr = tid / 16, c4 = (tid % 16) * 4;
            #pragma unroll
            for (int pp = 0; pp < 4; pp++)
                *(float4*)&Bs[(kr + pp * 16) * 64 + c4] =
                    *(const float4*)(Wg + (size_t)(kr + pp * 16) * 512 + h * 64 + c4);
        }
        __syncthreads();
        float acc1[2][4] = {};
        #pragma unroll 8
        for (int k = 0; k < 64; k++) {
            float a0 = As[k * 33 + ty * 2 + 0];
            float a1 = As[k * 33 + ty * 2 + 1];
            float4 b = *(const float4*)&Bs[k * 64 + tx * 4];
            acc1[0][0] += a0 * b.x; acc1[0][1] += a0 * b.y; acc1[0][2] += a0 * b.z; acc1[0][3] += a0 * b.w;
            acc1[1][0] += a1 * b.x; acc1[1][1] += a1 * b.y; acc1[1][2] += a1 * b.z; acc1[1][3] += a1 * b.w;
        }
        float4 bgv = *(const float4*)(bg + h * 64 + tx * 4);
        __syncthreads();   // GEMM1 done reading As/Bs
        #pragma unroll
        for (int i2 = 0; i2 < 2; i2++) {
            Cs[(ty * 2 + i2) * 65 + tx * 4 + 0] = fmaxf(acc1[i2][0] + bgv.x, 0.f);
            Cs[(ty * 2 + i2) * 65 + tx * 4 + 1] = fmaxf(acc1[i2][1] + bgv.y, 0.f);
            Cs[(ty * 2 + i2) * 65 + tx * 4 + 2] = fmaxf(acc1[i2][2] + bgv.z, 0.f);
            Cs[(ty * 2 + i2) * 65 + tx * 4 + 3] = fmaxf(acc1[i2][3] + bgv.w, 0.f);
        }
        {   // load Wh_h (64x64) into Bs
            int kr = tid / 16, c4 = (tid % 16) * 4;
            #pragma unroll
            for (int pp = 0; pp < 4; pp++)
                *(float4*)&Bs[(kr + pp * 16) * 64 + c4] =
                    *(const float4*)(Wh + (size_t)(h * 64 + kr + pp * 16) * 64 + c4);
        }
        __syncthreads();
        #pragma unroll 8
        for (int k = 0; k < 64; k++) {
            float a0 = Cs[(ty * 2 + 0) * 65 + k];
            float a1 = Cs[(ty * 2 + 1) * 65 + k];
            float4 b = *(const float4*)&Bs[k * 64 + tx * 4];
            accO[0][0] += a0 * b.x; accO[0][1] += a0 * b.y; accO[0][2] += a0 * b.z; accO[0][3] += a0 * b.w;
            accO[1][0] += a1 * b.x; accO[1][1] += a1 * b.y; accO[1][2] += a1 * b.z; accO[1][3] += a1 * b.w;
        }
        __syncthreads();   // done with Cs/Bs before next head
    }
    float4 bhv = *(const float4*)(bh + tx * 4);
    #pragma unroll
    for (int i2 = 0; i2 < 2; i2++) {
        float4 o;
        o.x = fmaxf(accO[i2][0] + bhv.x, 0.f);
        o.y = fmaxf(accO[i2][1] + bhv.y, 0.f);
        o.z = fmaxf(accO[i2][2] + bhv.z, 0.f);
        o.w = fmaxf(accO[i2][3] + bhv.w, 0.f);
        *(float4*)(out2 + (size_t)(r0 + ty * 2 + i2) * 64 + tx * 4) = o;
    }
}

// ---------------------------------------------------------------- Set2Set LSTM step
__global__ void k_lstm(const float* __restrict__ W_ih, const float* __restrict__ W_hh,
                       const float* __restrict__ b_ih, const float* __restrict__ b_hh,
                       const float* __restrict__ r_in, float* __restrict__ h, float* __restrict__ c) {
    int b = blockIdx.x;
    int g = threadIdx.x;
    __shared__ float gs[256];
    __shared__ float hs[64], rs_[64];
    if (g < 64) hs[g] = h[(size_t)b * 64 + g];
    else if (g < 128) rs_[g - 64] = r_in[(size_t)b * 64 + (g - 64)];
    __syncthreads();
    float acc = b_ih[g] + b_hh[g];
    const float* wi = W_ih + (size_t)g * 128;
    const float* wh = W_hh + (size_t)g * 64;
    #pragma unroll 8
    for (int k = 0; k < 64; k++) acc += hs[k] * (wi[k] + wh[k]) + rs_[k] * wi[64 + k];
    gs[g] = acc;
    __syncthreads();
    if (g < 64) {
        float ig = gs[g], fg = gs[64 + g], gg = gs[128 + g], og = gs[192 + g];
        float cc = c[(size_t)b * 64 + g];
        float si = 1.f / (1.f + __expf(-ig));
        float sf = 1.f / (1.f + __expf(-fg));
        float so = 1.f / (1.f + __expf(-og));
        float cn = sf * cc + si * tanhf(gg);
        c[(size_t)b * 64 + g] = cn;
        h[(size_t)b * 64 + g] = so * tanhf(cn);
    }
}

// ---------------------------------------------------------------- fused e2 + segment softmax + weighted reduce
__global__ __launch_bounds__(256) void k_segr(const float* __restrict__ out2,
                                              const float* __restrict__ hstate,
                                              const int* __restrict__ segst,
                                              float* __restrict__ r_out) {
    int b = blockIdx.x, tid = threadIdx.x, lane = tid & 63, w = tid >> 6;
    __shared__ float hl[64];
    __shared__ float red[4];
    __shared__ float wlds[2048];
    __shared__ float part[4][64];
    int beg = segst[b], end = segst[b + 1];
    if (tid < 64) hl[tid] = hstate[(size_t)b * 64 + tid];
    __syncthreads();
    // phase A: thread-per-row dot e2[i] = out2[i] . h[b]
    float ev[8];
    int nr = 0;
    float mloc = -1e30f;
    for (int i = beg + tid; i < end; i += 256) {
        const float4* op = (const float4*)(out2 + (size_t)i * 64);
        float d = 0.f;
        #pragma unroll
        for (int j = 0; j < 16; j++) {
            float4 o = op[j];
            float4 hv = *(const float4*)&hl[j * 4];
            d += o.x * hv.x + o.y * hv.y + o.z * hv.z + o.w * hv.w;
        }
        ev[nr++] = d;
        mloc = fmaxf(mloc, d);
    }
    #pragma unroll
    for (int off = 1; off < 64; off <<= 1) mloc = fmaxf(mloc, __shfl_xor(mloc, off));
    if (lane == 0) red[w] = mloc;
    __syncthreads();
    float m = fmaxf(fmaxf(red[0], red[1]), fmaxf(red[2], red[3]));
    __syncthreads();
    // phase B: exp weights -> LDS; block-sum
    float sloc = 0.f;
    {
        int k = 0;
        for (int i = beg + tid; i < end; i += 256) {
            float wv2 = __expf(ev[k++] - m);
            wlds[i - beg] = wv2;
            sloc += wv2;
        }
    }
    #pragma unroll
    for (int off = 1; off < 64; off <<= 1) sloc += __shfl_xor(sloc, off);
    if (lane == 0) red[w] = sloc;
    __syncthreads();
    float sv = red[0] + red[1] + red[2] + red[3];
    float inv = sv > 0.f ? 1.f / sv : 0.f;
    // phase C: weighted column sum
    float acc = 0.f;
    for (int i = beg + w; i < end; i += 4)
        acc += wlds[i - beg] * out2[(size_t)i * 64 + lane];
    part[w][lane] = acc;
    __syncthreads();
    if (w == 0)
        r_out[(size_t)b * 64 + lane] =
            (part[0][lane] + part[1][lane] + part[2][lane] + part[3][lane]) * inv;
}

__global__ void k_final(const float* __restrict__ h, const float* __restrict__ r,
                        const float* __restrict__ W1, const float* __restrict__ b1,
                        const float* __restrict__ W2, const float* __restrict__ b2,
                        float* __restrict__ out) {
    int b = blockIdx.x, j = threadIdx.x;
    float t = b1[j];
    const float* hb = h + (size_t)b * 64;
    const float* rb = r + (size_t)b * 64;
    #pragma unroll 8
    for (int k = 0; k < 64; k++)
        t += hb[k] * W1[(size_t)k * 64 + j] + rb[k] * W1[(size_t)(64 + k) * 64 + j];
    t = fmaxf(t, 0.f) * W2[j];
    #pragma unroll
    for (int off = 32; off > 0; off >>= 1) t += __shfl_xor(t, off);
    if (j == 0) out[b] = t + b2[0];
}

// ----------------------------------------------------------------
extern "C" void kernel_launch(void* const* d_in, const int* in_sizes, int n_in,
                              void* d_out, int out_size, void* d_ws, size_t ws_size,
                              hipStream_t stream) {
    const float* x     = (const float*)d_in[0];
    const int*   ei    = (const int*)d_in[1];
    const int*   batch = (const int*)d_in[2];
    const float* W0    = (const float*)d_in[3];
    const float* b0    = (const float*)d_in[4];
    const float* Wg    = (const float*)d_in[5];
    const float* att_s = (const float*)d_in[6];
    const float* att_d = (const float*)d_in[7];
    const float* bg    = (const float*)d_in[8];
    const float* Wh    = (const float*)d_in[9];
    const float* bh    = (const float*)d_in[10];
    const float* W_ih  = (const float*)d_in[11];
    const float* W_hh  = (const float*)d_in[12];
    const float* b_ih  = (const float*)d_in[13];
    const float* b_hh  = (const float*)d_in[14];
    const float* W1    = (const float*)d_in[15];
    const float* b1    = (const float*)d_in[16];
    const float* W2    = (const float*)d_in[17];
    const float* b2    = (const float*)d_in[18];
    float* out = (float*)d_out;

    const int* esrc = ei;
    const int* edst = ei + N_EDGES;

    char* wsb = (char*)d_ws;
    size_t off = 0;
    auto alloc = [&](size_t bytes) {
        void* p = wsb + off;
        off = (off + bytes + 255) & ~(size_t)255;
        return p;
    };
    float* h0      = (float*)alloc((size_t)N_NODES * 64 * 4);
    float* agg_pre = (float*)alloc((size_t)N_NODES * 512 * 4);
    float* out2    = (float*)alloc((size_t)N_NODES * 64 * 4);
    float* a_s     = (float*)alloc((size_t)N_NODES * 8 * 4);
    float* a_d     = (float*)alloc((size_t)N_NODES * 8 * 4);
    float* vsd     = (float*)alloc(64 * 16 * 4);
    int*   deg     = (int*)alloc((size_t)N_NODES * 4);
    int*   tmp     = (int*)alloc((size_t)N_NODES * 4);
    int*   bsum    = (int*)alloc(32 * 4);
    int*   offs    = (int*)alloc((size_t)(N_NODES + 1) * 4);
    int*   cursor  = (int*)alloc((size_t)N_NODES * 4);
    int*   adj     = (int*)alloc((size_t)(N_EDGES + N_NODES) * 4);
    int*   segst   = (int*)alloc((size_t)(NBATCH + 1) * 4);
    float* hstate  = (float*)alloc((size_t)NBATCH * 64 * 4);   // hstate/cstate/r0 contiguous (each 32 KB, 256B-aligned)
    float* cstate  = (float*)alloc((size_t)NBATCH * 64 * 4);
    float* r0      = (float*)alloc((size_t)NBATCH * 64 * 4);
    float* r1      = (float*)alloc((size_t)NBATCH * 64 * 4);

    // node MLP (+zero deg), tiny setup (vsd + bounds), attention dots (+zero h/c/r0)
    k_h0<<<(N_NODES + 3) / 4, 256, 0, stream>>>(x, W0, b0, h0, deg, N_NODES);
    k_small<<<2, 512, 0, stream>>>(Wg, att_s, att_d, vsd, batch, segst, N_NODES, NBATCH);
    k_asd<<<N_NODES / 16, 256, 0, stream>>>(h0, vsd, a_s, a_d, hstate);

    // CSR by dst (with self loops)
    k_count<<<(N_EDGES + 255) / 256, 256, 0, stream>>>(edst, deg, N_EDGES);
    const int nblk = (N_NODES + 1023) / 1024;
    k_scan1<<<nblk, 1024, 0, stream>>>(deg, tmp, bsum, N_NODES);
    k_scan2<<<(N_NODES + 256) / 256, 256, 0, stream>>>(tmp, bsum, offs, adj, cursor, N_NODES, nblk);
    k_fill_edge<<<(N_EDGES + 255) / 256, 256, 0, stream>>>(esrc, edst, cursor, adj, N_EDGES);

    // GAT aggregate (gathers h0) + fused double-GEMM
    k_gat2<<<N_NODES / 2, 256, 0, stream>>>(offs, adj, a_s, a_d, h0, agg_pre, N_NODES);
    k_fused<<<N_NODES / 32, 256, 0, stream>>>(agg_pre, Wg, bg, Wh, bh, out2);

    // Set2Set
    float* rin = r0;
    float* rout = r1;
    for (int it = 0; it < 3; it++) {
        k_lstm<<<NBATCH, 256, 0, stream>>>(W_ih, W_hh, b_ih, b_hh, rin, hstate, cstate);
        k_segr<<<NBATCH, 256, 0, stream>>>(out2, hstate, segst, rout);
        float* tmp2 = rin; rin = rout; rout = tmp2;
    }
    k_final<<<NBATCH, 64, 0, stream>>>(hstate, rin, W1, b1, W2, b2, out);
}

// Round 5
// 323.829 us; speedup vs baseline: 1.8583x; 1.0921x over previous
//
#include <hip/hip_runtime.h>

#define N_NODES 20000
#define N_EDGES 320000
#define NBATCH  128

__device__ __forceinline__ float lrelu(float v) { return v > 0.f ? v : 0.2f * v; }

// ---------------------------------------------------------------- h0 = relu(x@W0+b0); also zero deg
__global__ void k_h0(const float* __restrict__ x, const float* __restrict__ W0,
                     const float* __restrict__ b0, float* __restrict__ h0,
                     int* __restrict__ deg, int n) {
    __shared__ float ws[25 * 64];
    __shared__ float bs[64];
    __shared__ float xs[100];
    int t = threadIdx.x;
    int gid = blockIdx.x * 256 + t;
    if (gid < n) deg[gid] = 0;
    for (int i = t; i < 25 * 64; i += 256) ws[i] = W0[i];
    if (t < 64) bs[t] = b0[t];
    int nb = blockIdx.x * 4;
    if (t < 100 && nb * 25 + t < n * 25) xs[t] = x[(size_t)nb * 25 + t];
    __syncthreads();
    int node = nb + (t >> 6);
    int c = t & 63;
    if (node >= n) return;
    float s = bs[c];
    const float* xr = xs + (t >> 6) * 25;
    #pragma unroll
    for (int k = 0; k < 25; k++) s += xr[k] * ws[k * 64 + c];
    h0[(size_t)node * 64 + c] = fmaxf(s, 0.f);
}

// ---------------------------------------------------------------- merged tiny setup: vsd + segment bounds
__global__ void k_small(const float* __restrict__ Wg, const float* __restrict__ att_s,
                        const float* __restrict__ att_d, float* __restrict__ vsd,
                        const int* __restrict__ batch, int* __restrict__ segst, int n, int b) {
    int t = threadIdx.x;
    if (blockIdx.x == 0) {
        int k = t >> 3, h = t & 7;
        const float* wrow = Wg + (size_t)k * 512 + h * 64;
        float s1 = 0.f, s2 = 0.f;
        #pragma unroll 8
        for (int c = 0; c < 64; c++) {
            float w = wrow[c];
            s1 += w * att_s[h * 64 + c];
            s2 += w * att_d[h * 64 + c];
        }
        vsd[k * 16 + h] = s1;
        vsd[k * 16 + 8 + h] = s2;
    } else {
        if (t > b) return;
        int lo = 0, hi = n;
        while (lo < hi) { int mid = (lo + hi) >> 1; if (batch[mid] < t) lo = mid + 1; else hi = mid; }
        segst[t] = lo;
    }
}

// ---------------------------------------------------------------- [a_s|a_d] = h0 @ vsd; also zero h/c/r0
__global__ __launch_bounds__(256) void k_asd(const float* __restrict__ h0,
                                             const float* __restrict__ vsd,
                                             float* __restrict__ a_s, float* __restrict__ a_d,
                                             float* __restrict__ hcr) {
    __shared__ float hs[16][65];
    __shared__ float vl[64 * 16];
    int tid = threadIdx.x;
    int gid = blockIdx.x * 256 + tid;
    if (gid < 3 * NBATCH * 64) hcr[gid] = 0.f;
    int rbase = blockIdx.x * 16;
    {
        int row = tid / 16, c4 = (tid % 16) * 4;
        float4 hv = *(const float4*)(h0 + (size_t)(rbase + row) * 64 + c4);
        hs[row][c4] = hv.x; hs[row][c4 + 1] = hv.y; hs[row][c4 + 2] = hv.z; hs[row][c4 + 3] = hv.w;
    }
    #pragma unroll
    for (int j = 0; j < 4; j++) vl[tid + j * 256] = vsd[tid + j * 256];
    __syncthreads();
    int nl = tid / 16, o = tid % 16;
    float acc = 0.f;
    #pragma unroll 16
    for (int k = 0; k < 64; k++) acc += hs[nl][k] * vl[k * 16 + o];
    int node = rbase + nl;
    if (o < 8) a_s[node * 8 + o] = acc;
    else       a_d[node * 8 + (o - 8)] = acc;
}

// ---------------------------------------------------------------- CSR build
__global__ void k_count(const int* __restrict__ dst, int* __restrict__ deg, int e) {
    int i = blockIdx.x * 256 + threadIdx.x;
    if (i < e) atomicAdd(&deg[dst[i]], 1);
}

__global__ __launch_bounds__(1024) void k_scan1(const int* __restrict__ deg,
                                                int* __restrict__ tmp, int* __restrict__ bsum, int n) {
    __shared__ int wsum[16];
    int tid = threadIdx.x, lane = tid & 63, w = tid >> 6;
    int i = blockIdx.x * 1024 + tid;
    int v = (i < n) ? deg[i] + 1 : 0;   // +1 self loop
    int x = v;
    #pragma unroll
    for (int off = 1; off < 64; off <<= 1) {
        int t = __shfl_up(x, off);
        if (lane >= off) x += t;
    }
    if (lane == 63) wsum[w] = x;
    __syncthreads();
    int pre = 0;
    #pragma unroll
    for (int j = 0; j < 16; j++) if (j < w) pre += wsum[j];
    if (i < n) tmp[i] = pre + x - v;    // block-local exclusive
    if (tid == 1023) bsum[blockIdx.x] = pre + x;
}

// scan2 also writes the self-loop adjacency + its edge logits
__global__ void k_scan2(const int* __restrict__ tmp, const int* __restrict__ bsum,
                        const float* __restrict__ a_s, const float* __restrict__ a_d,
                        int* __restrict__ offs, int* __restrict__ adj,
                        int* __restrict__ cursor, float* __restrict__ eb, int n, int nblk) {
    int i = blockIdx.x * 256 + threadIdx.x;
    if (i > n) return;
    int b = i >> 10;
    int pre = 0;
    for (int j = 0; j < b; j++) pre += bsum[j];
    if (i == n) {
        int tot = pre;
        for (int j = b; j < nblk; j++) tot += bsum[j];
        offs[n] = tot;
        return;
    }
    int o = pre + tmp[i];
    offs[i] = o;
    adj[o] = i;          // self loop first
    cursor[i] = o + 1;
    float4 s0 = *(const float4*)(a_s + (size_t)i * 8);
    float4 s1 = *(const float4*)(a_s + (size_t)i * 8 + 4);
    float4 d0 = *(const float4*)(a_d + (size_t)i * 8);
    float4 d1 = *(const float4*)(a_d + (size_t)i * 8 + 4);
    float4 e0, e1;
    e0.x = lrelu(s0.x + d0.x); e0.y = lrelu(s0.y + d0.y);
    e0.z = lrelu(s0.z + d0.z); e0.w = lrelu(s0.w + d0.w);
    e1.x = lrelu(s1.x + d1.x); e1.y = lrelu(s1.y + d1.y);
    e1.z = lrelu(s1.z + d1.z); e1.w = lrelu(s1.w + d1.w);
    *(float4*)(eb + (size_t)o * 8) = e0;
    *(float4*)(eb + (size_t)o * 8 + 4) = e1;
}

// fill edges + compute per-position logits e[p][h]
__global__ void k_fill_edge(const int* __restrict__ src, const int* __restrict__ dst,
                            const float* __restrict__ a_s, const float* __restrict__ a_d,
                            int* __restrict__ cursor, int* __restrict__ adj,
                            float* __restrict__ eb, int e) {
    int i = blockIdx.x * 256 + threadIdx.x;
    if (i >= e) return;
    int s = src[i], d = dst[i];
    int p = atomicAdd(&cursor[d], 1);
    adj[p] = s;
    float4 s0 = *(const float4*)(a_s + (size_t)s * 8);
    float4 s1 = *(const float4*)(a_s + (size_t)s * 8 + 4);
    float4 d0 = *(const float4*)(a_d + (size_t)d * 8);
    float4 d1 = *(const float4*)(a_d + (size_t)d * 8 + 4);
    float4 e0, e1;
    e0.x = lrelu(s0.x + d0.x); e0.y = lrelu(s0.y + d0.y);
    e0.z = lrelu(s0.z + d0.z); e0.w = lrelu(s0.w + d0.w);
    e1.x = lrelu(s1.x + d1.x); e1.y = lrelu(s1.y + d1.y);
    e1.z = lrelu(s1.z + d1.z); e1.w = lrelu(s1.w + d1.w);
    *(float4*)(eb + (size_t)p * 8) = e0;
    *(float4*)(eb + (size_t)p * 8 + 4) = e1;
}

// ---------------------------------------------------------------- GAT: softmax + aggregate h0 (1 wave/node)
// eb[p*8+h] precomputed; lane = g*8+h for softmax phases, lane = channel for aggregation
__global__ __launch_bounds__(256) void k_gat3(const int* __restrict__ offs, const int* __restrict__ adj,
                                              const float* __restrict__ eb,
                                              const float* __restrict__ h0,
                                              float* __restrict__ agg_pre, int n) {
    int lane = threadIdx.x & 63;
    int node = blockIdx.x * 4 + (threadIdx.x >> 6);
    if (node >= n) return;
    int beg = offs[node], end = offs[node + 1];
    int g = lane >> 3;   // edge slot within 8-group

    // pass 1: online (m,s) per (g,h); fully coalesced eb reads
    float m = -1e30f, s = 0.f;
    for (int base = beg; base < end; base += 8) {
        if (base + g < end) {
            float ev = eb[(size_t)base * 8 + lane];
            if (ev > m) { s = s * __expf(m - ev) + 1.f; m = ev; }
            else        { s += __expf(ev - m); }
        }
    }
    #pragma unroll
    for (int off = 8; off < 64; off <<= 1) {
        float mo = __shfl_xor(m, off), so = __shfl_xor(s, off);
        float mn = fmaxf(m, mo);
        s = s * __expf(m - mn) + so * __expf(mo - mn);
        m = mn;
    }
    float rcp = 1.f / s;

    // pass 2: superchunks of 64 edges; batched adj load, batched alpha, pipelined row gathers
    float acc[8] = {0.f, 0.f, 0.f, 0.f, 0.f, 0.f, 0.f, 0.f};
    for (int sbase = beg; sbase < end; sbase += 64) {
        int scnt = end - sbase; if (scnt > 64) scnt = 64;
        int srcv = 0;
        if (lane < scnt) srcv = adj[sbase + lane];
        float al[8];
        #pragma unroll
        for (int j = 0; j < 8; j++) {
            int q = j * 8 + g;
            float ev = -1e30f;
            if (q < scnt) ev = eb[(size_t)sbase * 8 + j * 64 + lane];
            al[j] = __expf(ev - m) * rcp;   // 0 for padding lanes
        }
        for (int j = 0; j < 8; j++) {
            int qb = j * 8;
            if (qb >= scnt) break;
            int sg[8]; float xv[8];
            #pragma unroll
            for (int g2 = 0; g2 < 8; g2++) sg[g2] = __shfl(srcv, qb + g2);
            #pragma unroll
            for (int g2 = 0; g2 < 8; g2++)
                xv[g2] = h0[(size_t)sg[g2] * 64 + lane];   // alpha=0 masks padding
            #pragma unroll
            for (int g2 = 0; g2 < 8; g2++) {
                #pragma unroll
                for (int h2 = 0; h2 < 8; h2++)
                    acc[h2] += __shfl(al[j], g2 * 8 + h2) * xv[g2];
            }
        }
    }
    #pragma unroll
    for (int h2 = 0; h2 < 8; h2++)
        agg_pre[(size_t)node * 512 + h2 * 64 + lane] = acc[h2];
}

// ---------------------------------------------------------------- fused: out2 = relu( relu(agg_pre @h Wg + bg) @ Wh + bh )
__global__ __launch_bounds__(256) void k_fused(const float* __restrict__ agg_pre,
                                               const float* __restrict__ Wg,
                                               const float* __restrict__ bg,
                                               const float* __restrict__ Wh,
                                               const float* __restrict__ bh,
                                               float* __restrict__ out2) {
    __shared__ float As[64 * 33];   // A_h k-major: As[k*33 + r]
    __shared__ float Bs[64 * 64];   // Bs[k*64 + c]
    __shared__ float Cs[32 * 65];   // agg_h r-major: Cs[r*65 + k]
    int tid = threadIdx.x;
    int r0 = blockIdx.x * 32;
    int tx = tid % 16, ty = tid / 16;
    float accO[2][4] = {};
    for (int h = 0; h < 8; h++) {
        {
            int rr = tid / 16, k4 = (tid % 16) * 4;
            #pragma unroll
            for (int pp = 0; pp < 2; pp++) {
                int r = rr + pp * 16;
                float4 av = *(const float4*)(agg_pre + (size_t)(r0 + r) * 512 + h * 64 + k4);
                As[(k4 + 0) * 33 + r] = av.x;
                As[(k4 + 1) * 33 + r] = av.y;
                As[(k4 + 2) * 33 + r] = av.z;
                As[(k4 + 3) * 33 + r] = av.w;
            }
        }
        {
            int kr = tid / 16, c4 = (tid % 16) * 4;
            #pragma unroll
            for (int pp = 0; pp < 4; pp++)
                *(float4*)&Bs[(kr + pp * 16) * 64 + c4] =
                    *(const float4*)(Wg + (size_t)(kr + pp * 16) * 512 + h * 64 + c4);
        }
        __syncthreads();
        float acc1[2][4] = {};
        #pragma unroll 8
        for (int k = 0; k < 64; k++) {
            float a0 = As[k * 33 + ty * 2 + 0];
            float a1 = As[k * 33 + ty * 2 + 1];
            float4 b = *(const float4*)&Bs[k * 64 + tx * 4];
            acc1[0][0] += a0 * b.x; acc1[0][1] += a0 * b.y; acc1[0][2] += a0 * b.z; acc1[0][3] += a0 * b.w;
            acc1[1][0] += a1 * b.x; acc1[1][1] += a1 * b.y; acc1[1][2] += a1 * b.z; acc1[1][3] += a1 * b.w;
        }
        float4 bgv = *(const float4*)(bg + h * 64 + tx * 4);
        __syncthreads();
        #pragma unroll
        for (int i2 = 0; i2 < 2; i2++) {
            Cs[(ty * 2 + i2) * 65 + tx * 4 + 0] = fmaxf(acc1[i2][0] + bgv.x, 0.f);
            Cs[(ty * 2 + i2) * 65 + tx * 4 + 1] = fmaxf(acc1[i2][1] + bgv.y, 0.f);
            Cs[(ty * 2 + i2) * 65 + tx * 4 + 2] = fmaxf(acc1[i2][2] + bgv.z, 0.f);
            Cs[(ty * 2 + i2) * 65 + tx * 4 + 3] = fmaxf(acc1[i2][3] + bgv.w, 0.f);
        }
        {
            int kr = tid / 16, c4 = (tid % 16) * 4;
            #pragma unroll
            for (int pp = 0; pp < 4; pp++)
                *(float4*)&Bs[(kr + pp * 16) * 64 + c4] =
                    *(const float4*)(Wh + (size_t)(h * 64 + kr + pp * 16) * 64 + c4);
        }
        __syncthreads();
        #pragma unroll 8
        for (int k = 0; k < 64; k++) {
            float a0 = Cs[(ty * 2 + 0) * 65 + k];
            float a1 = Cs[(ty * 2 + 1) * 65 + k];
            float4 b = *(const float4*)&Bs[k * 64 + tx * 4];
            accO[0][0] += a0 * b.x; accO[0][1] += a0 * b.y; accO[0][2] += a0 * b.z; accO[0][3] += a0 * b.w;
            accO[1][0] += a1 * b.x; accO[1][1] += a1 * b.y; accO[1][2] += a1 * b.z; accO[1][3] += a1 * b.w;
        }
        __syncthreads();
    }
    float4 bhv = *(const float4*)(bh + tx * 4);
    #pragma unroll
    for (int i2 = 0; i2 < 2; i2++) {
        float4 o;
        o.x = fmaxf(accO[i2][0] + bhv.x, 0.f);
        o.y = fmaxf(accO[i2][1] + bhv.y, 0.f);
        o.z = fmaxf(accO[i2][2] + bhv.z, 0.f);
        o.w = fmaxf(accO[i2][3] + bhv.w, 0.f);
        *(float4*)(out2 + (size_t)(r0 + ty * 2 + i2) * 64 + tx * 4) = o;
    }
}

// ---------------------------------------------------------------- Set2Set LSTM step
__global__ void k_lstm(const float* __restrict__ W_ih, const float* __restrict__ W_hh,
                       const float* __restrict__ b_ih, const float* __restrict__ b_hh,
                       const float* __restrict__ r_in, float* __restrict__ h, float* __restrict__ c) {
    int b = blockIdx.x;
    int g = threadIdx.x;
    __shared__ float gs[256];
    __shared__ float hs[64], rs_[64];
    if (g < 64) hs[g] = h[(size_t)b * 64 + g];
    else if (g < 128) rs_[g - 64] = r_in[(size_t)b * 64 + (g - 64)];
    __syncthreads();
    float acc = b_ih[g] + b_hh[g];
    const float* wi = W_ih + (size_t)g * 128;
    const float* wh = W_hh + (size_t)g * 64;
    #pragma unroll 8
    for (int k = 0; k < 64; k++) acc += hs[k] * (wi[k] + wh[k]) + rs_[k] * wi[64 + k];
    gs[g] = acc;
    __syncthreads();
    if (g < 64) {
        float ig = gs[g], fg = gs[64 + g], gg = gs[128 + g], og = gs[192 + g];
        float cc = c[(size_t)b * 64 + g];
        float si = 1.f / (1.f + __expf(-ig));
        float sf = 1.f / (1.f + __expf(-fg));
        float so = 1.f / (1.f + __expf(-og));
        float cn = sf * cc + si * tanhf(gg);
        c[(size_t)b * 64 + g] = cn;
        h[(size_t)b * 64 + g] = so * tanhf(cn);
    }
}

// ---------------------------------------------------------------- fused e2 + segment softmax + weighted reduce
__global__ __launch_bounds__(256) void k_segr(const float* __restrict__ out2,
                                              const float* __restrict__ hstate,
                                              const int* __restrict__ segst,
                                              float* __restrict__ r_out) {
    int b = blockIdx.x, tid = threadIdx.x, lane = tid & 63, w = tid >> 6;
    __shared__ float hl[64];
    __shared__ float red[4];
    __shared__ float wlds[2048];
    __shared__ float part[4][64];
    int beg = segst[b], end = segst[b + 1];
    if (tid < 64) hl[tid] = hstate[(size_t)b * 64 + tid];
    __syncthreads();
    float ev[8];
    int nr = 0;
    float mloc = -1e30f;
    for (int i = beg + tid; i < end; i += 256) {
        const float4* op = (const float4*)(out2 + (size_t)i * 64);
        float d = 0.f;
        #pragma unroll
        for (int j = 0; j < 16; j++) {
            float4 o = op[j];
            float4 hv = *(const float4*)&hl[j * 4];
            d += o.x * hv.x + o.y * hv.y + o.z * hv.z + o.w * hv.w;
        }
        ev[nr++] = d;
        mloc = fmaxf(mloc, d);
    }
    #pragma unroll
    for (int off = 1; off < 64; off <<= 1) mloc = fmaxf(mloc, __shfl_xor(mloc, off));
    if (lane == 0) red[w] = mloc;
    __syncthreads();
    float m = fmaxf(fmaxf(red[0], red[1]), fmaxf(red[2], red[3]));
    __syncthreads();
    float sloc = 0.f;
    {
        int k = 0;
        for (int i = beg + tid; i < end; i += 256) {
            float wv2 = __expf(ev[k++] - m);
            wlds[i - beg] = wv2;
            sloc += wv2;
        }
    }
    #pragma unroll
    for (int off = 1; off < 64; off <<= 1) sloc += __shfl_xor(sloc, off);
    if (lane == 0) red[w] = sloc;
    __syncthreads();
    float sv = red[0] + red[1] + red[2] + red[3];
    float inv = sv > 0.f ? 1.f / sv : 0.f;
    float acc = 0.f;
    for (int i = beg + w; i < end; i += 4)
        acc += wlds[i - beg] * out2[(size_t)i * 64 + lane];
    part[w][lane] = acc;
    __syncthreads();
    if (w == 0)
        r_out[(size_t)b * 64 + lane] =
            (part[0][lane] + part[1][lane] + part[2][lane] + part[3][lane]) * inv;
}

__global__ void k_final(const float* __restrict__ h, const float* __restrict__ r,
                        const float* __restrict__ W1, const float* __restrict__ b1,
                        const float* __restrict__ W2, const float* __restrict__ b2,
                        float* __restrict__ out) {
    int b = blockIdx.x, j = threadIdx.x;
    float t = b1[j];
    const float* hb = h + (size_t)b * 64;
    const float* rb = r + (size_t)b * 64;
    #pragma unroll 8
    for (int k = 0; k < 64; k++)
        t += hb[k] * W1[(size_t)k * 64 + j] + rb[k] * W1[(size_t)(64 + k) * 64 + j];
    t = fmaxf(t, 0.f) * W2[j];
    #pragma unroll
    for (int off = 32; off > 0; off >>= 1) t += __shfl_xor(t, off);
    if (j == 0) out[b] = t + b2[0];
}

// ----------------------------------------------------------------
extern "C" void kernel_launch(void* const* d_in, const int* in_sizes, int n_in,
                              void* d_out, int out_size, void* d_ws, size_t ws_size,
                              hipStream_t stream) {
    const float* x     = (const float*)d_in[0];
    const int*   ei    = (const int*)d_in[1];
    const int*   batch = (const int*)d_in[2];
    const float* W0    = (const float*)d_in[3];
    const float* b0    = (const float*)d_in[4];
    const float* Wg    = (const float*)d_in[5];
    const float* att_s = (const float*)d_in[6];
    const float* att_d = (const float*)d_in[7];
    const float* bg    = (const float*)d_in[8];
    const float* Wh    = (const float*)d_in[9];
    const float* bh    = (const float*)d_in[10];
    const float* W_ih  = (const float*)d_in[11];
    const float* W_hh  = (const float*)d_in[12];
    const float* b_ih  = (const float*)d_in[13];
    const float* b_hh  = (const float*)d_in[14];
    const float* W1    = (const float*)d_in[15];
    const float* b1    = (const float*)d_in[16];
    const float* W2    = (const float*)d_in[17];
    const float* b2    = (const float*)d_in[18];
    float* out = (float*)d_out;

    const int* esrc = ei;
    const int* edst = ei + N_EDGES;

    char* wsb = (char*)d_ws;
    size_t off = 0;
    auto alloc = [&](size_t bytes) {
        void* p = wsb + off;
        off = (off + bytes + 255) & ~(size_t)255;
        return p;
    };
    float* h0      = (float*)alloc((size_t)N_NODES * 64 * 4);
    float* agg_pre = (float*)alloc((size_t)N_NODES * 512 * 4);
    float* out2    = (float*)alloc((size_t)N_NODES * 64 * 4);
    float* a_s     = (float*)alloc((size_t)N_NODES * 8 * 4);
    float* a_d     = (float*)alloc((size_t)N_NODES * 8 * 4);
    float* vsd     = (float*)alloc(64 * 16 * 4);
    float* eb      = (float*)alloc((size_t)(N_EDGES + N_NODES) * 8 * 4);
    int*   deg     = (int*)alloc((size_t)N_NODES * 4);
    int*   tmp     = (int*)alloc((size_t)N_NODES * 4);
    int*   bsum    = (int*)alloc(32 * 4);
    int*   offs    = (int*)alloc((size_t)(N_NODES + 1) * 4);
    int*   cursor  = (int*)alloc((size_t)N_NODES * 4);
    int*   adj     = (int*)alloc((size_t)(N_EDGES + N_NODES) * 4);
    int*   segst   = (int*)alloc((size_t)(NBATCH + 1) * 4);
    float* hstate  = (float*)alloc((size_t)NBATCH * 64 * 4);   // hstate/cstate/r0 contiguous
    float* cstate  = (float*)alloc((size_t)NBATCH * 64 * 4);
    float* r0      = (float*)alloc((size_t)NBATCH * 64 * 4);
    float* r1      = (float*)alloc((size_t)NBATCH * 64 * 4);

    // node MLP (+zero deg), tiny setup (vsd + bounds), attention dots (+zero h/c/r0)
    k_h0<<<(N_NODES + 3) / 4, 256, 0, stream>>>(x, W0, b0, h0, deg, N_NODES);
    k_small<<<2, 512, 0, stream>>>(Wg, att_s, att_d, vsd, batch, segst, N_NODES, NBATCH);
    k_asd<<<N_NODES / 16, 256, 0, stream>>>(h0, vsd, a_s, a_d, hstate);

    // CSR by dst (with self loops) + per-position logits
    k_count<<<(N_EDGES + 255) / 256, 256, 0, stream>>>(edst, deg, N_EDGES);
    const int nblk = (N_NODES + 1023) / 1024;
    k_scan1<<<nblk, 1024, 0, stream>>>(deg, tmp, bsum, N_NODES);
    k_scan2<<<(N_NODES + 256) / 256, 256, 0, stream>>>(tmp, bsum, a_s, a_d, offs, adj, cursor, eb, N_NODES, nblk);
    k_fill_edge<<<(N_EDGES + 255) / 256, 256, 0, stream>>>(esrc, edst, a_s, a_d, cursor, adj, eb, N_EDGES);

    // GAT aggregate (gathers h0) + fused double-GEMM
    k_gat3<<<(N_NODES + 3) / 4, 256, 0, stream>>>(offs, adj, eb, h0, agg_pre, N_NODES);
    k_fused<<<N_NODES / 32, 256, 0, stream>>>(agg_pre, Wg, bg, Wh, bh, out2);

    // Set2Set
    float* rin = r0;
    float* rout = r1;
    for (int it = 0; it < 3; it++) {
        k_lstm<<<NBATCH, 256, 0, stream>>>(W_ih, W_hh, b_ih, b_hh, rin, hstate, cstate);
        k_segr<<<NBATCH, 256, 0, stream>>>(out2, hstate, segst, rout);
        float* tmp2 = rin; rin = rout; rout = tmp2;
    }
    k_final<<<NBATCH, 64, 0, stream>>>(hstate, rin, W1, b1, W2, b2, out);
}

// Round 6
// 306.590 us; speedup vs baseline: 1.9628x; 1.0562x over previous
//
#include <hip/hip_runtime.h>

#define N_NODES 20000
#define N_EDGES 320000
#define NBATCH  128

__device__ __forceinline__ float lrelu(float v) { return v > 0.f ? v : 0.2f * v; }

// ---------------------------------------------------------------- h0 = relu(x@W0+b0); also zero deg
__global__ void k_h0(const float* __restrict__ x, const float* __restrict__ W0,
                     const float* __restrict__ b0, float* __restrict__ h0,
                     int* __restrict__ deg, int n) {
    __shared__ float ws[25 * 64];
    __shared__ float bs[64];
    __shared__ float xs[100];
    int t = threadIdx.x;
    int gid = blockIdx.x * 256 + t;
    if (gid < n) deg[gid] = 0;
    for (int i = t; i < 25 * 64; i += 256) ws[i] = W0[i];
    if (t < 64) bs[t] = b0[t];
    int nb = blockIdx.x * 4;
    if (t < 100 && nb * 25 + t < n * 25) xs[t] = x[(size_t)nb * 25 + t];
    __syncthreads();
    int node = nb + (t >> 6);
    int c = t & 63;
    if (node >= n) return;
    float s = bs[c];
    const float* xr = xs + (t >> 6) * 25;
    #pragma unroll
    for (int k = 0; k < 25; k++) s += xr[k] * ws[k * 64 + c];
    h0[(size_t)node * 64 + c] = fmaxf(s, 0.f);
}

// ---------------------------------------------------------------- merged tiny setup: vsd + segment bounds
__global__ void k_small(const float* __restrict__ Wg, const float* __restrict__ att_s,
                        const float* __restrict__ att_d, float* __restrict__ vsd,
                        const int* __restrict__ batch, int* __restrict__ segst, int n, int b) {
    int t = threadIdx.x;
    if (blockIdx.x == 0) {
        int k = t >> 3, h = t & 7;
        const float* wrow = Wg + (size_t)k * 512 + h * 64;
        float s1 = 0.f, s2 = 0.f;
        #pragma unroll 8
        for (int c = 0; c < 64; c++) {
            float w = wrow[c];
            s1 += w * att_s[h * 64 + c];
            s2 += w * att_d[h * 64 + c];
        }
        vsd[k * 16 + h] = s1;
        vsd[k * 16 + 8 + h] = s2;
    } else {
        if (t > b) return;
        int lo = 0, hi = n;
        while (lo < hi) { int mid = (lo + hi) >> 1; if (batch[mid] < t) lo = mid + 1; else hi = mid; }
        segst[t] = lo;
    }
}

// ---------------------------------------------------------------- [a_s|a_d] = h0 @ vsd
__global__ __launch_bounds__(256) void k_asd(const float* __restrict__ h0,
                                             const float* __restrict__ vsd,
                                             float* __restrict__ a_s, float* __restrict__ a_d) {
    __shared__ float hs[16][65];
    __shared__ float vl[64 * 16];
    int tid = threadIdx.x;
    int rbase = blockIdx.x * 16;
    {
        int row = tid / 16, c4 = (tid % 16) * 4;
        float4 hv = *(const float4*)(h0 + (size_t)(rbase + row) * 64 + c4);
        hs[row][c4] = hv.x; hs[row][c4 + 1] = hv.y; hs[row][c4 + 2] = hv.z; hs[row][c4 + 3] = hv.w;
    }
    #pragma unroll
    for (int j = 0; j < 4; j++) vl[tid + j * 256] = vsd[tid + j * 256];
    __syncthreads();
    int nl = tid / 16, o = tid % 16;
    float acc = 0.f;
    #pragma unroll 16
    for (int k = 0; k < 64; k++) acc += hs[nl][k] * vl[k * 16 + o];
    int node = rbase + nl;
    if (o < 8) a_s[node * 8 + o] = acc;
    else       a_d[node * 8 + (o - 8)] = acc;
}

// ---------------------------------------------------------------- CSR build
__global__ void k_count(const int* __restrict__ dst, int* __restrict__ deg, int e) {
    int i = blockIdx.x * 256 + threadIdx.x;
    if (i < e) atomicAdd(&deg[dst[i]], 1);
}

__global__ __launch_bounds__(1024) void k_scan1(const int* __restrict__ deg,
                                                int* __restrict__ tmp, int* __restrict__ bsum, int n) {
    __shared__ int wsum[16];
    int tid = threadIdx.x, lane = tid & 63, w = tid >> 6;
    int i = blockIdx.x * 1024 + tid;
    int v = (i < n) ? deg[i] + 1 : 0;   // +1 self loop
    int x = v;
    #pragma unroll
    for (int off = 1; off < 64; off <<= 1) {
        int t = __shfl_up(x, off);
        if (lane >= off) x += t;
    }
    if (lane == 63) wsum[w] = x;
    __syncthreads();
    int pre = 0;
    #pragma unroll
    for (int j = 0; j < 16; j++) if (j < w) pre += wsum[j];
    if (i < n) tmp[i] = pre + x - v;
    if (tid == 1023) bsum[blockIdx.x] = pre + x;
}

__global__ void k_scan2(const int* __restrict__ tmp, const int* __restrict__ bsum,
                        const float* __restrict__ a_s, const float* __restrict__ a_d,
                        int* __restrict__ offs, int* __restrict__ adj,
                        int* __restrict__ cursor, float* __restrict__ eb, int n, int nblk) {
    int i = blockIdx.x * 256 + threadIdx.x;
    if (i > n) return;
    int b = i >> 10;
    int pre = 0;
    for (int j = 0; j < b; j++) pre += bsum[j];
    if (i == n) {
        int tot = pre;
        for (int j = b; j < nblk; j++) tot += bsum[j];
        offs[n] = tot;
        return;
    }
    int o = pre + tmp[i];
    offs[i] = o;
    adj[o] = i;          // self loop first
    cursor[i] = o + 1;
    float4 s0 = *(const float4*)(a_s + (size_t)i * 8);
    float4 s1 = *(const float4*)(a_s + (size_t)i * 8 + 4);
    float4 d0 = *(const float4*)(a_d + (size_t)i * 8);
    float4 d1 = *(const float4*)(a_d + (size_t)i * 8 + 4);
    float4 e0, e1;
    e0.x = lrelu(s0.x + d0.x); e0.y = lrelu(s0.y + d0.y);
    e0.z = lrelu(s0.z + d0.z); e0.w = lrelu(s0.w + d0.w);
    e1.x = lrelu(s1.x + d1.x); e1.y = lrelu(s1.y + d1.y);
    e1.z = lrelu(s1.z + d1.z); e1.w = lrelu(s1.w + d1.w);
    *(float4*)(eb + (size_t)o * 8) = e0;
    *(float4*)(eb + (size_t)o * 8 + 4) = e1;
}

__global__ void k_fill_edge(const int* __restrict__ src, const int* __restrict__ dst,
                            const float* __restrict__ a_s, const float* __restrict__ a_d,
                            int* __restrict__ cursor, int* __restrict__ adj,
                            float* __restrict__ eb, int e) {
    int i = blockIdx.x * 256 + threadIdx.x;
    if (i >= e) return;
    int s = src[i], d = dst[i];
    int p = atomicAdd(&cursor[d], 1);
    adj[p] = s;
    float4 s0 = *(const float4*)(a_s + (size_t)s * 8);
    float4 s1 = *(const float4*)(a_s + (size_t)s * 8 + 4);
    float4 d0 = *(const float4*)(a_d + (size_t)d * 8);
    float4 d1 = *(const float4*)(a_d + (size_t)d * 8 + 4);
    float4 e0, e1;
    e0.x = lrelu(s0.x + d0.x); e0.y = lrelu(s0.y + d0.y);
    e0.z = lrelu(s0.z + d0.z); e0.w = lrelu(s0.w + d0.w);
    e1.x = lrelu(s1.x + d1.x); e1.y = lrelu(s1.y + d1.y);
    e1.z = lrelu(s1.z + d1.z); e1.w = lrelu(s1.w + d1.w);
    *(float4*)(eb + (size_t)p * 8) = e0;
    *(float4*)(eb + (size_t)p * 8 + 4) = e1;
}

// ---------------------------------------------------------------- GAT: softmax + aggregate h0 (1 wave/node)
__global__ __launch_bounds__(256) void k_gat3(const int* __restrict__ offs, const int* __restrict__ adj,
                                              const float* __restrict__ eb,
                                              const float* __restrict__ h0,
                                              float* __restrict__ agg_pre, int n) {
    int lane = threadIdx.x & 63;
    int node = blockIdx.x * 4 + (threadIdx.x >> 6);
    if (node >= n) return;
    int beg = offs[node], end = offs[node + 1];
    int g = lane >> 3;

    float m = -1e30f, s = 0.f;
    for (int base = beg; base < end; base += 8) {
        if (base + g < end) {
            float ev = eb[(size_t)base * 8 + lane];
            if (ev > m) { s = s * __expf(m - ev) + 1.f; m = ev; }
            else        { s += __expf(ev - m); }
        }
    }
    #pragma unroll
    for (int off = 8; off < 64; off <<= 1) {
        float mo = __shfl_xor(m, off), so = __shfl_xor(s, off);
        float mn = fmaxf(m, mo);
        s = s * __expf(m - mn) + so * __expf(mo - mn);
        m = mn;
    }
    float rcp = 1.f / s;

    float acc[8] = {0.f, 0.f, 0.f, 0.f, 0.f, 0.f, 0.f, 0.f};
    for (int sbase = beg; sbase < end; sbase += 64) {
        int scnt = end - sbase; if (scnt > 64) scnt = 64;
        int srcv = 0;
        if (lane < scnt) srcv = adj[sbase + lane];
        float al[8];
        #pragma unroll
        for (int j = 0; j < 8; j++) {
            int q = j * 8 + g;
            float ev = -1e30f;
            if (q < scnt) ev = eb[(size_t)sbase * 8 + j * 64 + lane];
            al[j] = __expf(ev - m) * rcp;
        }
        for (int j = 0; j < 8; j++) {
            int qb = j * 8;
            if (qb >= scnt) break;
            int sg[8]; float xv[8];
            #pragma unroll
            for (int g2 = 0; g2 < 8; g2++) sg[g2] = __shfl(srcv, qb + g2);
            #pragma unroll
            for (int g2 = 0; g2 < 8; g2++)
                xv[g2] = h0[(size_t)sg[g2] * 64 + lane];
            #pragma unroll
            for (int g2 = 0; g2 < 8; g2++) {
                #pragma unroll
                for (int h2 = 0; h2 < 8; h2++)
                    acc[h2] += __shfl(al[j], g2 * 8 + h2) * xv[g2];
            }
        }
    }
    #pragma unroll
    for (int h2 = 0; h2 < 8; h2++)
        agg_pre[(size_t)node * 512 + h2 * 64 + lane] = acc[h2];
}

// ---------------------------------------------------------------- fused head-pair GEMM -> partials
// block: 32 rows x 2 heads (heads 2*by, 2*by+1); part[by] += relu(A_h@Wg_h+bg)@Wh_h
__global__ __launch_bounds__(256) void k_fused2(const float* __restrict__ agg_pre,
                                                const float* __restrict__ Wg,
                                                const float* __restrict__ bg,
                                                const float* __restrict__ Wh,
                                                float* __restrict__ part, int M) {
    __shared__ float As[64 * 33];
    __shared__ float Bs[64 * 64];
    __shared__ float Cs[32 * 65];
    int tid = threadIdx.x;
    int r0 = blockIdx.x * 32;
    int tx = tid % 16, ty = tid / 16;
    float accO[2][4] = {};
    #pragma unroll
    for (int hh2 = 0; hh2 < 2; hh2++) {
        int h = blockIdx.y * 2 + hh2;
        {
            int rr = tid / 16, k4 = (tid % 16) * 4;
            #pragma unroll
            for (int pp = 0; pp < 2; pp++) {
                int r = rr + pp * 16;
                float4 av = *(const float4*)(agg_pre + (size_t)(r0 + r) * 512 + h * 64 + k4);
                As[(k4 + 0) * 33 + r] = av.x;
                As[(k4 + 1) * 33 + r] = av.y;
                As[(k4 + 2) * 33 + r] = av.z;
                As[(k4 + 3) * 33 + r] = av.w;
            }
        }
        {
            int kr = tid / 16, c4 = (tid % 16) * 4;
            #pragma unroll
            for (int pp = 0; pp < 4; pp++)
                *(float4*)&Bs[(kr + pp * 16) * 64 + c4] =
                    *(const float4*)(Wg + (size_t)(kr + pp * 16) * 512 + h * 64 + c4);
        }
        __syncthreads();
        float acc1[2][4] = {};
        #pragma unroll 8
        for (int k = 0; k < 64; k++) {
            float a0 = As[k * 33 + ty * 2 + 0];
            float a1 = As[k * 33 + ty * 2 + 1];
            float4 b = *(const float4*)&Bs[k * 64 + tx * 4];
            acc1[0][0] += a0 * b.x; acc1[0][1] += a0 * b.y; acc1[0][2] += a0 * b.z; acc1[0][3] += a0 * b.w;
            acc1[1][0] += a1 * b.x; acc1[1][1] += a1 * b.y; acc1[1][2] += a1 * b.z; acc1[1][3] += a1 * b.w;
        }
        float4 bgv = *(const float4*)(bg + h * 64 + tx * 4);
        __syncthreads();
        #pragma unroll
        for (int i2 = 0; i2 < 2; i2++) {
            Cs[(ty * 2 + i2) * 65 + tx * 4 + 0] = fmaxf(acc1[i2][0] + bgv.x, 0.f);
            Cs[(ty * 2 + i2) * 65 + tx * 4 + 1] = fmaxf(acc1[i2][1] + bgv.y, 0.f);
            Cs[(ty * 2 + i2) * 65 + tx * 4 + 2] = fmaxf(acc1[i2][2] + bgv.z, 0.f);
            Cs[(ty * 2 + i2) * 65 + tx * 4 + 3] = fmaxf(acc1[i2][3] + bgv.w, 0.f);
        }
        {
            int kr = tid / 16, c4 = (tid % 16) * 4;
            #pragma unroll
            for (int pp = 0; pp < 4; pp++)
                *(float4*)&Bs[(kr + pp * 16) * 64 + c4] =
                    *(const float4*)(Wh + (size_t)(h * 64 + kr + pp * 16) * 64 + c4);
        }
        __syncthreads();
        #pragma unroll 8
        for (int k = 0; k < 64; k++) {
            float a0 = Cs[(ty * 2 + 0) * 65 + k];
            float a1 = Cs[(ty * 2 + 1) * 65 + k];
            float4 b = *(const float4*)&Bs[k * 64 + tx * 4];
            accO[0][0] += a0 * b.x; accO[0][1] += a0 * b.y; accO[0][2] += a0 * b.z; accO[0][3] += a0 * b.w;
            accO[1][0] += a1 * b.x; accO[1][1] += a1 * b.y; accO[1][2] += a1 * b.z; accO[1][3] += a1 * b.w;
        }
        __syncthreads();
    }
    float* Cb = part + (size_t)blockIdx.y * M * 64;
    #pragma unroll
    for (int i2 = 0; i2 < 2; i2++) {
        float4 o;
        o.x = accO[i2][0]; o.y = accO[i2][1]; o.z = accO[i2][2]; o.w = accO[i2][3];
        *(float4*)(Cb + (size_t)(r0 + ty * 2 + i2) * 64 + tx * 4) = o;
    }
}

// reduce 4 partials + bias + relu
__global__ void k_reduce4(const float* __restrict__ part, const float* __restrict__ bias,
                          float* __restrict__ out, int M) {
    int idx = blockIdx.x * 256 + threadIdx.x;
    if (idx >= M * 16) return;
    int r = idx / 16, cq = idx % 16;
    float4 s = make_float4(0.f, 0.f, 0.f, 0.f);
    #pragma unroll
    for (int y = 0; y < 4; y++) {
        float4 p = *(const float4*)(part + ((size_t)y * M + r) * 64 + cq * 4);
        s.x += p.x; s.y += p.y; s.z += p.z; s.w += p.w;
    }
    float4 b = *(const float4*)(bias + cq * 4);
    s.x = fmaxf(s.x + b.x, 0.f); s.y = fmaxf(s.y + b.y, 0.f);
    s.z = fmaxf(s.z + b.z, 0.f); s.w = fmaxf(s.w + b.w, 0.f);
    *(float4*)(out + (size_t)r * 64 + cq * 4) = s;
}

// ---------------------------------------------------------------- whole Set2Set (3 iters) + final MLP, 1 block / batch elem
#define SROWS 208
__global__ __launch_bounds__(256) void k_s2s(const float* __restrict__ out2,
                                             const int* __restrict__ segst,
                                             const float* __restrict__ W_ih, const float* __restrict__ W_hh,
                                             const float* __restrict__ b_ih, const float* __restrict__ b_hh,
                                             const float* __restrict__ W1, const float* __restrict__ b1,
                                             const float* __restrict__ W2, const float* __restrict__ b2,
                                             float* __restrict__ out) {
    int b = blockIdx.x, tid = threadIdx.x, lane = tid & 63, w = tid >> 6;
    __shared__ float sc[SROWS * 65];   // cached segment rows, stride 65 (conflict-free both ways)
    __shared__ float wlds[1024];
    __shared__ float hl[64], cl[64], rl[64];
    __shared__ float red[4];
    __shared__ float gsh[256];
    int beg = segst[b], end = segst[b + 1];
    int nrows = end - beg;
    int ncache = nrows < SROWS ? nrows : SROWS;
    for (int idx = tid; idx < ncache * 16; idx += 256) {
        int r = idx >> 4, q = idx & 15;
        float4 v = *(const float4*)(out2 + (size_t)(beg + r) * 64 + q * 4);
        float* p = &sc[r * 65 + q * 4];
        p[0] = v.x; p[1] = v.y; p[2] = v.z; p[3] = v.w;
    }
    if (tid < 64) { hl[tid] = 0.f; cl[tid] = 0.f; rl[tid] = 0.f; }
    __syncthreads();

    for (int it = 0; it < 3; it++) {
        // LSTM: gate per thread
        {
            float acc = b_ih[tid] + b_hh[tid];
            const float* wi = W_ih + (size_t)tid * 128;
            const float* wh = W_hh + (size_t)tid * 64;
            #pragma unroll 8
            for (int k = 0; k < 64; k++) acc += hl[k] * (wi[k] + wh[k]) + rl[k] * wi[64 + k];
            gsh[tid] = acc;
        }
        __syncthreads();
        if (tid < 64) {
            float ig = gsh[tid], fg = gsh[64 + tid], gg = gsh[128 + tid], og = gsh[192 + tid];
            float cc = cl[tid];
            float si = 1.f / (1.f + __expf(-ig));
            float sf = 1.f / (1.f + __expf(-fg));
            float so = 1.f / (1.f + __expf(-og));
            float cn = sf * cc + si * tanhf(gg);
            cl[tid] = cn;
            hl[tid] = so * tanhf(cn);
        }
        __syncthreads();
        // phase A: e per row (thread-per-row), block max
        float ev[4];
        int nr = 0;
        float mloc = -1e30f;
        for (int i = tid; i < nrows; i += 256) {
            float d = 0.f;
            if (i < SROWS) {
                const float* rp = &sc[i * 65];
                #pragma unroll 16
                for (int j = 0; j < 64; j++) d += rp[j] * hl[j];
            } else {
                const float* rp = out2 + (size_t)(beg + i) * 64;
                for (int j = 0; j < 64; j++) d += rp[j] * hl[j];
            }
            ev[nr++] = d;
            mloc = fmaxf(mloc, d);
        }
        #pragma unroll
        for (int off = 1; off < 64; off <<= 1) mloc = fmaxf(mloc, __shfl_xor(mloc, off));
        if (lane == 0) red[w] = mloc;
        __syncthreads();
        float m = fmaxf(fmaxf(red[0], red[1]), fmaxf(red[2], red[3]));
        __syncthreads();
        // phase B: exp -> wlds, block sum
        float sloc = 0.f;
        nr = 0;
        for (int i = tid; i < nrows; i += 256) {
            float wv = __expf(ev[nr++] - m);
            if (i < 1024) wlds[i] = wv;
            sloc += wv;
        }
        #pragma unroll
        for (int off = 1; off < 64; off <<= 1) sloc += __shfl_xor(sloc, off);
        if (lane == 0) red[w] = sloc;
        __syncthreads();
        float sv = red[0] + red[1] + red[2] + red[3];
        float inv = sv > 0.f ? 1.f / sv : 0.f;
        // phase C: r = softmax-weighted column sum
        float acc = 0.f;
        for (int i = w; i < nrows; i += 4) {
            float v = (i < SROWS) ? sc[i * 65 + lane] : out2[(size_t)(beg + i) * 64 + lane];
            acc += wlds[i] * v;
        }
        gsh[w * 64 + lane] = acc;
        __syncthreads();
        if (tid < 64)
            rl[tid] = (gsh[tid] + gsh[64 + tid] + gsh[128 + tid] + gsh[192 + tid]) * inv;
        __syncthreads();
    }
    // final MLP: y = relu([h|r]@W1+b1)@W2 + b2
    if (tid < 64) {
        float t = b1[tid];
        #pragma unroll 8
        for (int k = 0; k < 64; k++)
            t += hl[k] * W1[(size_t)k * 64 + tid] + rl[k] * W1[(size_t)(64 + k) * 64 + tid];
        t = fmaxf(t, 0.f) * W2[tid];
        #pragma unroll
        for (int off = 32; off > 0; off >>= 1) t += __shfl_xor(t, off);
        if (tid == 0) out[b] = t + b2[0];
    }
}

// ----------------------------------------------------------------
extern "C" void kernel_launch(void* const* d_in, const int* in_sizes, int n_in,
                              void* d_out, int out_size, void* d_ws, size_t ws_size,
                              hipStream_t stream) {
    const float* x     = (const float*)d_in[0];
    const int*   ei    = (const int*)d_in[1];
    const int*   batch = (const int*)d_in[2];
    const float* W0    = (const float*)d_in[3];
    const float* b0    = (const float*)d_in[4];
    const float* Wg    = (const float*)d_in[5];
    const float* att_s = (const float*)d_in[6];
    const float* att_d = (const float*)d_in[7];
    const float* bg    = (const float*)d_in[8];
    const float* Wh    = (const float*)d_in[9];
    const float* bh    = (const float*)d_in[10];
    const float* W_ih  = (const float*)d_in[11];
    const float* W_hh  = (const float*)d_in[12];
    const float* b_ih  = (const float*)d_in[13];
    const float* b_hh  = (const float*)d_in[14];
    const float* W1    = (const float*)d_in[15];
    const float* b1    = (const float*)d_in[16];
    const float* W2    = (const float*)d_in[17];
    const float* b2    = (const float*)d_in[18];
    float* out = (float*)d_out;

    const int* esrc = ei;
    const int* edst = ei + N_EDGES;

    char* wsb = (char*)d_ws;
    size_t off = 0;
    auto alloc = [&](size_t bytes) {
        void* p = wsb + off;
        off = (off + bytes + 255) & ~(size_t)255;
        return p;
    };
    float* h0      = (float*)alloc((size_t)N_NODES * 64 * 4);
    float* agg_pre = (float*)alloc((size_t)N_NODES * 512 * 4);
    float* part    = (float*)alloc((size_t)4 * N_NODES * 64 * 4);
    float* out2    = (float*)alloc((size_t)N_NODES * 64 * 4);
    float* a_s     = (float*)alloc((size_t)N_NODES * 8 * 4);
    float* a_d     = (float*)alloc((size_t)N_NODES * 8 * 4);
    float* vsd     = (float*)alloc(64 * 16 * 4);
    float* eb      = (float*)alloc((size_t)(N_EDGES + N_NODES) * 8 * 4);
    int*   deg     = (int*)alloc((size_t)N_NODES * 4);
    int*   tmp     = (int*)alloc((size_t)N_NODES * 4);
    int*   bsum    = (int*)alloc(32 * 4);
    int*   offs    = (int*)alloc((size_t)(N_NODES + 1) * 4);
    int*   cursor  = (int*)alloc((size_t)N_NODES * 4);
    int*   adj     = (int*)alloc((size_t)(N_EDGES + N_NODES) * 4);
    int*   segst   = (int*)alloc((size_t)(NBATCH + 1) * 4);

    // node MLP (+zero deg), tiny setup (vsd + bounds), attention dots
    k_h0<<<(N_NODES + 3) / 4, 256, 0, stream>>>(x, W0, b0, h0, deg, N_NODES);
    k_small<<<2, 512, 0, stream>>>(Wg, att_s, att_d, vsd, batch, segst, N_NODES, NBATCH);
    k_asd<<<N_NODES / 16, 256, 0, stream>>>(h0, vsd, a_s, a_d);

    // CSR by dst (with self loops) + per-position logits
    k_count<<<(N_EDGES + 255) / 256, 256, 0, stream>>>(edst, deg, N_EDGES);
    const int nblk = (N_NODES + 1023) / 1024;
    k_scan1<<<nblk, 1024, 0, stream>>>(deg, tmp, bsum, N_NODES);
    k_scan2<<<(N_NODES + 256) / 256, 256, 0, stream>>>(tmp, bsum, a_s, a_d, offs, adj, cursor, eb, N_NODES, nblk);
    k_fill_edge<<<(N_EDGES + 255) / 256, 256, 0, stream>>>(esrc, edst, a_s, a_d, cursor, adj, eb, N_EDGES);

    // GAT aggregate + fused head-pair double-GEMM (partials) + reduce
    k_gat3<<<(N_NODES + 3) / 4, 256, 0, stream>>>(offs, adj, eb, h0, agg_pre, N_NODES);
    k_fused2<<<dim3(N_NODES / 32, 4), 256, 0, stream>>>(agg_pre, Wg, bg, Wh, part, N_NODES);
    k_reduce4<<<(N_NODES * 16 + 255) / 256, 256, 0, stream>>>(part, bh, out2, N_NODES);

    // Set2Set (3 iters) + final MLP, one kernel
    k_s2s<<<NBATCH, 256, 0, stream>>>(out2, segst, W_ih, W_hh, b_ih, b_hh, W1, b1, W2, b2, out);
}